// Round 9
// baseline (193.128 us; speedup 1.0000x reference)
//
#include <hip/hip_runtime.h>
#include <hip/hip_bf16.h>

#define B_    16
#define CIN_  128
#define COUT_ 256
#define H_    80
#define W_    80
#define HO_   40
#define WO_   40
#define KK_   9
#define SK_   1152      // CIN_*KK_
#define NPIX_ 25600     // B_*HO_*WO_
#define NKS_  36        // K / 32

typedef __attribute__((ext_vector_type(8))) short short8;
typedef __attribute__((ext_vector_type(4))) float floatx4;

__device__ __forceinline__ unsigned short f2bu(float v) {
  __hip_bfloat16 h = __float2bfloat16(v);
  return *reinterpret_cast<unsigned short*>(&h);
}
__device__ __forceinline__ float bu2f(unsigned short u) {
  return __uint_as_float(((unsigned)u) << 16);
}
__device__ __forceinline__ unsigned int pk2(float a, float b) {
  return (unsigned)f2bu(a) | ((unsigned)f2bu(b) << 16);
}
// async global->LDS DMA, 16B per lane. LDS dest = wave-uniform base + lane*16.
__device__ __forceinline__ void gl_lds16(const unsigned short* g, unsigned short* l) {
  __builtin_amdgcn_global_load_lds(
      (const __attribute__((address_space(1))) unsigned int*)(const void*)g,
      (__attribute__((address_space(3))) unsigned int*)(void*)l, 16, 0, 0);
}

// ------------------------------------------------- KT: pack weights for MFMA
// Layout v4: Apk[ks(36)][m(256)][slot(4)][j(8)]; slot of row m holds k-quad
// qd = (slot - (m>>1)) & 3 (bank rotation -> conflict-free ds_read_b128).
// Also zeroes BN accumulators.
__global__ __launch_bounds__(256) void k_pack(const float* __restrict__ dw,
                                              unsigned short* __restrict__ Apk,
                                              float* __restrict__ accum) {
  int t = blockIdx.x * 256 + threadIdx.x;   // 0..294911
  if (t < 2 * COUT_) accum[t] = 0.f;
  int j  = t & 7;
  int sl = (t >> 3) & 3;
  int m  = (t >> 5) & 255;
  int ks = t >> 13;
  int qd = (sl - (m >> 1)) & 3;
  int k  = ks * 32 + qd * 8 + j;
  int kk = k >> 7, ci = k & 127;
  Apk[t] = f2bu(dw[m * SK_ + ci * KK_ + kk]);
}

// --------------- KC v2: x -> channels-last bf16 + fused offset conv
// (verified) XCD-affine by b (b%8 == xcd of writer); packed-pair LDS tile.
__global__ __launch_bounds__(256) void k_cl(const float* __restrict__ x,
                                            const float* __restrict__ ow,
                                            const float* __restrict__ ob,
                                            unsigned short* __restrict__ xcl,
                                            float* __restrict__ off) {
  __shared__ unsigned int ts[CIN_ * 41];   // 21 KB: word xw holds x=2xw (lo), 2xw+1 (hi)
  __shared__ float owl[18 * CIN_];         // 9.2 KB
  __shared__ float obl[18];
  const int tid = threadIdx.x;
  const int bid = blockIdx.x;              // 0..1279
  const int xcd = bid & 7;
  const int i0_ = bid >> 3;                // 0..159
  const int b   = (i0_ / 80) * 8 + xcd;
  const int y   = i0_ % 80;
  const bool even = (y & 1) == 0;

  // phase 1: coalesced float4 read along x, packed bf16 write into LDS
  for (int j = tid; j < CIN_ * 20; j += 256) {
    int ci = j / 20, xq = j % 20;
    float4 v = *(const float4*)&x[(((size_t)b * CIN_ + ci) * H_ + y) * W_ + xq * 4];
    ts[ci * 41 + xq * 2 + 0] = pk2(v.x, v.y);
    ts[ci * 41 + xq * 2 + 1] = pk2(v.z, v.w);
  }
  if (even) {
    for (int j = tid; j < 18 * CIN_; j += 256) owl[j] = ow[j];
    if (tid < 18) obl[tid] = ob[tid];
  }
  __syncthreads();

  // phase 2: transpose out of LDS; global stores 256B-contiguous per 32 lanes
  unsigned short* op = xcl + ((size_t)b * H_ * W_ + (size_t)y * W_) * CIN_;
  for (int j = tid; j < 40 * 32; j += 256) {
    int xw = j >> 5, cg = j & 31;          // xw = x-pair, cg = 4-channel group
    unsigned w0 = ts[(cg * 4 + 0) * 41 + xw];
    unsigned w1 = ts[(cg * 4 + 1) * 41 + xw];
    unsigned w2 = ts[(cg * 4 + 2) * 41 + xw];
    unsigned w3 = ts[(cg * 4 + 3) * 41 + xw];
    uint2 lo = make_uint2((w0 & 0xFFFFu) | (w1 << 16),
                          (w2 & 0xFFFFu) | (w3 << 16));
    uint2 hi = make_uint2((w0 >> 16) | (w1 & 0xFFFF0000u),
                          (w2 >> 16) | (w3 & 0xFFFF0000u));
    *(uint2*)(op + (size_t)(2 * xw) * CIN_ + cg * 4)     = lo;
    *(uint2*)(op + (size_t)(2 * xw + 1) * CIN_ + cg * 4) = hi;
  }

  // fused offset conv (even y): x at even positions = low half of word wo
  if (even) {
    const int ho = y >> 1;
    for (int i = tid; i < 18 * WO_; i += 256) {
      int o = i / WO_, wo = i - o * WO_;
      float acc = obl[o];
      const float* wr = &owl[o * CIN_];
#pragma unroll 4
      for (int ci = 0; ci < CIN_; ci++)
        acc += wr[ci] * bu2f((unsigned short)(ts[ci * 41 + wo] & 0xFFFFu));
      off[((b * 18 + o) * HO_ + ho) * WO_ + wo] = acc;
    }
  }
}

// --- K2 v9 "fused, depth-2 gather, SAFE A-schedule": v8 failed because
// STAGE_A(t+3) with 3 buffers wrote the buffer being read ((t+3)%3==t%3).
// Fix: A-stage back to v7's proven depth-2 (STAGE_A(t+2), 3 buffers,
// lead < buffers), gather keeps depth-2 via two named register sets.
// Issue-order sim: prologue A0,G0,A1,G1 (16 out); body t issues G(t+2),
// A(t+2) (8 ops); top of body t queue=[G(t),A(t),G(t+1),A(t+1)] ->
// steady vmcnt(8), body 35 vmcnt(0). Buffer safety: stage into (t-1)%3
// is issued post-barrier(t); every wave crossed barrier(t) only after
// lgkmcnt(0) drained its reads of that buffer (v7-verified discipline).
// Block = 256ch x 64px, 400 blocks, 4 waves, acc[8][2], 74 KB LDS.
__global__ __launch_bounds__(256) void k_fused(const unsigned short* __restrict__ Apk,
                                               const unsigned short* __restrict__ xcl,
                                               const float* __restrict__ off,
                                               float* __restrict__ out,
                                               float* __restrict__ accum) {
  __shared__ __align__(16) unsigned short a_sh[3][8192];  // 48 KB: 256ch x 32k x3
  __shared__ __align__(16) unsigned short b_sh[2][2048];  // 8 KB:  64px x 32k x2
  __shared__ __align__(16) int   pidx4[576][4];           // 9.2 KB corner idx
  __shared__ __align__(16) float pw4[576][4];             // 9.2 KB corner wts

  const int tid = threadIdx.x;
  const int wv = tid >> 6;
  const int ln = tid & 63;
  const int lm = ln & 15;
  const int qd = ln >> 4;
  const int wch = wv & 1;              // channel half (2)
  const int wpx = wv >> 1;             // pixel half (2)

  const int bid = blockIdx.x;          // 0..399
  const int xcd = bid & 7;
  const int T   = bid >> 3;            // 0..49
  const int b   = xcd + 8 * (T / 25);  // b%8 == xcd: matches k_cl L2 affinity
  const int tl  = T % 25;              // 64-px tile within batch (25*64=1600)

  // ---- meta: 64 px x 9 kk -> 4 corner offsets (abs elem idx) + 4 weights
  for (int j = tid; j < 576; j += 256) {
    int ipx = j / 9, kk = j - ipx * 9;
    int g  = tl * 64 + ipx;            // pixel within batch, 0..1599
    int ho = g / 40, wo = g - ho * 40;
    float dy = off[((b * 18 + 2 * kk) * HO_ + ho) * WO_ + wo];
    float dx = off[((b * 18 + 2 * kk + 1) * HO_ + ho) * WO_ + wo];
    float py  = (float)(2 * ho - 1 + (kk / 3)) + dy;
    float pxf = (float)(2 * wo - 1 + (kk % 3)) + dx;
    float y0f = floorf(py), x0f = floorf(pxf);
    float wy1 = py - y0f, wx1 = pxf - x0f;
    float wy0 = 1.f - wy1, wx0 = 1.f - wx1;
    int y0 = (int)y0f, x0 = (int)x0f;
    int y1 = y0 + 1, x1 = x0 + 1;
    bool vy0 = (y0 >= 0) && (y0 < H_), vy1 = (y1 >= 0) && (y1 < H_);
    bool vx0 = (x0 >= 0) && (x0 < W_), vx1 = (x1 >= 0) && (x1 < W_);
    int y0c = min(max(y0, 0), H_ - 1), y1c = min(max(y1, 0), H_ - 1);
    int x0c = min(max(x0, 0), W_ - 1), x1c = min(max(x1, 0), W_ - 1);
    int base = b * (H_ * W_ * CIN_);
    pidx4[j][0] = base + (y0c * W_ + x0c) * CIN_;  pw4[j][0] = (vy0 && vx0) ? wy0 * wx0 : 0.f;
    pidx4[j][1] = base + (y0c * W_ + x1c) * CIN_;  pw4[j][1] = (vy0 && vx1) ? wy0 * wx1 : 0.f;
    pidx4[j][2] = base + (y1c * W_ + x0c) * CIN_;  pw4[j][2] = (vy1 && vx0) ? wy1 * wx0 : 0.f;
    pidx4[j][3] = base + (y1c * W_ + x1c) * CIN_;  pw4[j][3] = (vy1 && vx1) ? wy1 * wx1 : 0.f;
  }
  __syncthreads();

#define STAGE_A(t, bf) do {                                                    \
    const unsigned short* s_ = Apk + (size_t)(t) * 8192 + wv * 2048 + ln * 8;  \
    gl_lds16(s_ + 0 * 512, &a_sh[bf][wv * 2048 + 0 * 512]);                    \
    gl_lds16(s_ + 1 * 512, &a_sh[bf][wv * 2048 + 1 * 512]);                    \
    gl_lds16(s_ + 2 * 512, &a_sh[bf][wv * 2048 + 2 * 512]);                    \
    gl_lds16(s_ + 3 * 512, &a_sh[bf][wv * 2048 + 3 * 512]);                    \
  } while (0)

// wave wv gathers the B granule-set for pt-group wv: lane (qd,lm) -> px lm,
// channels (t&3)*32 + qd*8 .. +8 of kernel tap t>>2 (old sampler contract).
#define GATHER(t, I_, W_, c00_, c01_, c10_, c11_) do {                         \
    int kk_ = (t) >> 2, ci0_ = ((t) & 3) * 32;                                 \
    int mi_ = ((wv << 4) + lm) * 9 + kk_;                                      \
    I_ = *(const int4*)&pidx4[mi_][0];                                         \
    W_ = *(const float4*)&pw4[mi_][0];                                         \
    int co_ = ci0_ + qd * 8;                                                   \
    c00_ = *(const short8*)(xcl + I_.x + co_);                                 \
    c01_ = *(const short8*)(xcl + I_.y + co_);                                 \
    c10_ = *(const short8*)(xcl + I_.z + co_);                                 \
    c11_ = *(const short8*)(xcl + I_.w + co_);                                 \
  } while (0)

// one K-step: wait for this step's data, blend, publish B, prefetch
// G(t+2) into the SAME named set, STAGE_A(t+2) into buffer (t+2)%3, MFMA.
#define BODY(t, I_, W_, c00_, c01_, c10_, c11_) do {                           \
    if ((t) == NKS_ - 1) asm volatile("s_waitcnt vmcnt(0)" ::: "memory");      \
    else                 asm volatile("s_waitcnt vmcnt(8)" ::: "memory");      \
    short8 rb;                                                                 \
    _Pragma("unroll")                                                          \
    for (int i2 = 0; i2 < 8; i2++) {                                           \
      float v = W_.x * bu2f((unsigned short)c00_[i2]) +                        \
                W_.y * bu2f((unsigned short)c01_[i2]) +                        \
                W_.z * bu2f((unsigned short)c10_[i2]) +                        \
                W_.w * bu2f((unsigned short)c11_[i2]);                         \
      rb[i2] = (short)f2bu(v);                                                 \
    }                                                                          \
    *(short8*)&b_sh[(t) & 1][wv * 512 + ln * 8] = rb;                          \
    asm volatile("s_waitcnt lgkmcnt(0)" ::: "memory");                         \
    __builtin_amdgcn_s_barrier();                                              \
    if ((t) + 2 < NKS_) {                                                      \
      GATHER((t) + 2, I_, W_, c00_, c01_, c10_, c11_);                         \
      STAGE_A((t) + 2, ((t) + 2) % 3);                                         \
    }                                                                          \
    const unsigned short* al = &a_sh[(t) % 3][abase];                          \
    const unsigned short* bl = &b_sh[(t) & 1][bbase];                          \
    short8 av[8], bv[2];                                                       \
    _Pragma("unroll")                                                          \
    for (int mt = 0; mt < 8; mt++) av[mt] = *(const short8*)(al + mt * 512);   \
    _Pragma("unroll")                                                          \
    for (int nt = 0; nt < 2; nt++) bv[nt] = *(const short8*)(bl + nt * 512);   \
    _Pragma("unroll")                                                          \
    for (int mt = 0; mt < 8; mt++)                                             \
      _Pragma("unroll")                                                        \
      for (int nt = 0; nt < 2; nt++)                                           \
        acc[mt][nt] = __builtin_amdgcn_mfma_f32_16x16x32_bf16(av[mt], bv[nt],  \
                                                              acc[mt][nt],     \
                                                              0, 0, 0);        \
  } while (0)

  floatx4 acc[8][2];
#pragma unroll
  for (int mt = 0; mt < 8; mt++)
#pragma unroll
    for (int nt = 0; nt < 2; nt++) acc[mt][nt] = (floatx4){0.f, 0.f, 0.f, 0.f};

  // two named gather sets (rule #20: static register naming, no runtime idx)
  int4 eI, oI; float4 eW, oW;
  short8 e00, e01, e10, e11, o00, o01, o10, o11;
  const int slot  = (qd + (lm >> 1)) & 3;               // A bank rotation
  const int abase = (wch * 128 + lm) * 32 + slot * 8;   // + mt*512
  const int bbase = (wpx * 2) * 512 + ln * 8;           // + nt*512

  // prologue issue order (vmcnt accounting): A0, G0, A1, G1  (16 outstanding)
  STAGE_A(0, 0);
  GATHER(0, eI, eW, e00, e01, e10, e11);
  STAGE_A(1, 1);
  GATHER(1, oI, oW, o00, o01, o10, o11);

#pragma unroll 1
  for (int t = 0; t < NKS_; t += 2) {
    BODY(t,     eI, eW, e00, e01, e10, e11);
    BODY(t + 1, oI, oW, o00, o01, o10, o11);
  }
#undef STAGE_A
#undef GATHER
#undef BODY

  // ---- C write: c = wch*128 + mt*16 + qd*4 + r; px = b*1600 + tl*64 + ...
  const int cb0 = wch * 128;
  float* ob = out + (size_t)b * COUT_ * 1600;
#pragma unroll
  for (int nt = 0; nt < 2; nt++) {
    const int rem = tl * 64 + (wpx * 2 + nt) * 16 + lm;
#pragma unroll
    for (int mt = 0; mt < 8; mt++) {
#pragma unroll
      for (int r = 0; r < 4; r++)
        ob[(size_t)(cb0 + mt * 16 + qd * 4 + r) * 1600 + rem] = acc[mt][nt][r];
    }
  }

  // ---- fused BN stats over this block's 64 px, all 256 ch
  __syncthreads();                      // a_sh dead; reuse as reduction buffer
  float* red = (float*)&a_sh[0][0];     // 512 floats: s1[256], s2[256]
  if (tid < 256) { red[tid] = 0.f; red[256 + tid] = 0.f; }
  __syncthreads();
#pragma unroll
  for (int mt = 0; mt < 8; mt++) {
#pragma unroll
    for (int r = 0; r < 4; r++) {
      float s = acc[mt][0][r] + acc[mt][1][r];
      float q = acc[mt][0][r] * acc[mt][0][r] + acc[mt][1][r] * acc[mt][1][r];
#pragma unroll
      for (int d = 1; d < 16; d <<= 1) {
        s += __shfl_xor(s, d, 16);
        q += __shfl_xor(q, d, 16);
      }
      if (lm == 0) {
        int lc = cb0 + mt * 16 + qd * 4 + r;
        atomicAdd(&red[lc], s);
        atomicAdd(&red[256 + lc], q);
      }
    }
  }
  __syncthreads();
  if (tid < 256) {
    atomicAdd(&accum[tid],         red[tid]);
    atomicAdd(&accum[COUT_ + tid], red[256 + tid]);
  }
}

// --------------------------- K3: BN + SiLU in place on the final out buffer
__global__ __launch_bounds__(256) void k_bn(float* __restrict__ io0,
                                            const float* __restrict__ accum,
                                            const float* __restrict__ gamma,
                                            const float* __restrict__ beta) {
  const int t = blockIdx.x * 256 + threadIdx.x;
  const int i0 = t * 4;
  const int c = (i0 / (HO_ * WO_)) % COUT_;
  const float mean = accum[c] * (1.f / NPIX_);
  const float var  = accum[COUT_ + c] * (1.f / NPIX_) - mean * mean;
  const float inv  = rsqrtf(var + 1e-5f);
  const float g  = gamma[c] * inv;
  const float be = beta[c] - mean * g;
  float4 r0 = *(const float4*)(io0 + i0);
  float v[4] = {r0.x, r0.y, r0.z, r0.w};
#pragma unroll
  for (int q = 0; q < 4; q++) {
    float u = v[q] * g + be;
    v[q] = u / (1.f + expf(-u));
  }
  *(float4*)(io0 + i0) = make_float4(v[0], v[1], v[2], v[3]);
}

// ----------------------------------------------------------------- launcher
extern "C" void kernel_launch(void* const* d_in, const int* in_sizes, int n_in,
                              void* d_out, int out_size, void* d_ws, size_t ws_size,
                              hipStream_t stream) {
  const float* x     = (const float*)d_in[0];
  const float* ow    = (const float*)d_in[1];
  const float* ob    = (const float*)d_in[2];
  const float* dw    = (const float*)d_in[3];
  const float* gamma = (const float*)d_in[5];
  const float* beta  = (const float*)d_in[6];
  float* out = (float*)d_out;

  float* off   = (float*)d_ws;                                 // 460800 f
  float* accum = off + B_ * 18 * HO_ * WO_;                    // 512 f
  unsigned short* Apk = (unsigned short*)(accum + 2 * COUT_);  // 294912 us
  unsigned short* xcl = Apk + (size_t)SK_ * COUT_;             // 13107200 us

  k_pack<<<SK_, 256, 0, stream>>>(dw, Apk, accum);
  k_cl<<<B_ * H_, 256, 0, stream>>>(x, ow, ob, xcl, off);
  k_fused<<<400, 256, 0, stream>>>(Apk, xcl, off, out, accum);
  k_bn<<<(NPIX_ * COUT_ / 4 + 255) / 256, 256, 0, stream>>>(
      out, accum, gamma, beta);
}

// Round 10
// 190.426 us; speedup vs baseline: 1.0142x; 1.0142x over previous
//
#include <hip/hip_runtime.h>
#include <hip/hip_bf16.h>

#define B_    16
#define CIN_  128
#define COUT_ 256
#define H_    80
#define W_    80
#define HO_   40
#define WO_   40
#define KK_   9
#define SK_   1152      // CIN_*KK_
#define NPIX_ 25600     // B_*HO_*WO_
#define NKS_  36        // K / 32

typedef __attribute__((ext_vector_type(8))) short short8;
typedef __attribute__((ext_vector_type(4))) float floatx4;

__device__ __forceinline__ unsigned short f2bu(float v) {
  __hip_bfloat16 h = __float2bfloat16(v);
  return *reinterpret_cast<unsigned short*>(&h);
}
__device__ __forceinline__ float bu2f(unsigned short u) {
  return __uint_as_float(((unsigned)u) << 16);
}
__device__ __forceinline__ unsigned int pk2(float a, float b) {
  return (unsigned)f2bu(a) | ((unsigned)f2bu(b) << 16);
}
// async global->LDS DMA, 16B per lane. LDS dest = wave-uniform base + lane*16.
__device__ __forceinline__ void gl_lds16(const unsigned short* g, unsigned short* l) {
  __builtin_amdgcn_global_load_lds(
      (const __attribute__((address_space(1))) unsigned int*)(const void*)g,
      (__attribute__((address_space(3))) unsigned int*)(void*)l, 16, 0, 0);
}

// ------------------------------------------------- KT: pack weights for MFMA
// Layout v4: Apk[ks(36)][m(256)][slot(4)][j(8)]; slot of row m holds k-quad
// qd = (slot - (m>>1)) & 3 (bank rotation -> conflict-free ds_read_b128).
// Also zeroes BN accumulators.
__global__ __launch_bounds__(256) void k_pack(const float* __restrict__ dw,
                                              unsigned short* __restrict__ Apk,
                                              float* __restrict__ accum) {
  int t = blockIdx.x * 256 + threadIdx.x;   // 0..294911
  if (t < 2 * COUT_) accum[t] = 0.f;
  int j  = t & 7;
  int sl = (t >> 3) & 3;
  int m  = (t >> 5) & 255;
  int ks = t >> 13;
  int qd = (sl - (m >> 1)) & 3;
  int k  = ks * 32 + qd * 8 + j;
  int kk = k >> 7, ci = k & 127;
  Apk[t] = f2bu(dw[m * SK_ + ci * KK_ + kk]);
}

// --------------- KC v3: x -> channels-last bf16 (PURE transpose).
// The offset-conv tail (previously run by even-y blocks only: a serial
// scalar-LDS 18x40x128 loop while odd-y blocks idled past it) moved to k_off.
// All 1280 blocks now uniform; 21 KB LDS. XCD-affine by b (b%8 == bid&7).
__global__ __launch_bounds__(256) void k_cl(const float* __restrict__ x,
                                            unsigned short* __restrict__ xcl) {
  __shared__ unsigned int ts[CIN_ * 41];   // 21 KB: word xw holds x=2xw (lo), 2xw+1 (hi)
  const int tid = threadIdx.x;
  const int bid = blockIdx.x;              // 0..1279
  const int xcd = bid & 7;
  const int i0_ = bid >> 3;                // 0..159
  const int b   = (i0_ / 80) * 8 + xcd;
  const int y   = i0_ % 80;

  // phase 1: coalesced float4 read along x, packed bf16 write into LDS
  for (int j = tid; j < CIN_ * 20; j += 256) {
    int ci = j / 20, xq = j % 20;
    float4 v = *(const float4*)&x[(((size_t)b * CIN_ + ci) * H_ + y) * W_ + xq * 4];
    ts[ci * 41 + xq * 2 + 0] = pk2(v.x, v.y);
    ts[ci * 41 + xq * 2 + 1] = pk2(v.z, v.w);
  }
  __syncthreads();

  // phase 2: transpose out of LDS; global stores 256B-contiguous per 32 lanes
  unsigned short* op = xcl + ((size_t)b * H_ * W_ + (size_t)y * W_) * CIN_;
  for (int j = tid; j < 40 * 32; j += 256) {
    int xw = j >> 5, cg = j & 31;          // xw = x-pair, cg = 4-channel group
    unsigned w0 = ts[(cg * 4 + 0) * 41 + xw];
    unsigned w1 = ts[(cg * 4 + 1) * 41 + xw];
    unsigned w2 = ts[(cg * 4 + 2) * 41 + xw];
    unsigned w3 = ts[(cg * 4 + 3) * 41 + xw];
    uint2 lo = make_uint2((w0 & 0xFFFFu) | (w1 << 16),
                          (w2 & 0xFFFFu) | (w3 << 16));
    uint2 hi = make_uint2((w0 >> 16) | (w1 & 0xFFFF0000u),
                          (w2 >> 16) | (w3 & 0xFFFF0000u));
    *(uint2*)(op + (size_t)(2 * xw) * CIN_ + cg * 4)     = lo;
    *(uint2*)(op + (size_t)(2 * xw + 1) * CIN_ + cg * 4) = hi;
  }
}

// --------------- K_OFF: offset conv from channels-last bf16 xcl.
// Block = (b, ho): 640 blocks, XCD-affine (b%8 == bid&7 matches k_cl writer).
// Stages 40 even pixels x 128 ch (10.4 KB, row stride 65 words -> adjacent
// lanes hit adjacent banks; dup-wo lanes broadcast) + weights (9 KB).
// All 256 threads compute the 720 (o,wo) outputs; accumulation order over
// ci is ascending — bit-identical to the old fused tail.
__global__ __launch_bounds__(256) void k_off(const unsigned short* __restrict__ xcl,
                                             const float* __restrict__ ow,
                                             const float* __restrict__ ob,
                                             float* __restrict__ off) {
  __shared__ unsigned int xs_l[40][65];    // packed ch-pairs, +1 pad word
  __shared__ float owl[18 * CIN_];
  __shared__ float obl[18];
  const int tid = threadIdx.x;
  const int bid = blockIdx.x;              // 0..639
  const int xcd = bid & 7;
  const int r   = bid >> 3;                // 0..79
  const int b   = xcd + 8 * (r / 40);
  const int ho  = r % 40;

  const unsigned short* xr = xcl + ((size_t)b * (H_ * W_) + (size_t)(2 * ho) * W_) * CIN_;
  for (int j = tid; j < 40 * 32; j += 256) {
    int wo = j >> 5, seg = j & 31;         // seg = 4-channel group
    uint2 v = *(const uint2*)(xr + (size_t)(2 * wo) * CIN_ + seg * 4);
    xs_l[wo][seg * 2 + 0] = v.x;
    xs_l[wo][seg * 2 + 1] = v.y;
  }
  for (int j = tid; j < 18 * CIN_; j += 256) owl[j] = ow[j];
  if (tid < 18) obl[tid] = ob[tid];
  __syncthreads();

  for (int t = tid; t < 18 * 40; t += 256) {
    int o = t / 40, wo = t - o * 40;
    float acc = obl[o];
    const float* wr = &owl[o * CIN_];
#pragma unroll 8
    for (int i = 0; i < 64; i++) {
      unsigned int pr = xs_l[wo][i];
      acc += wr[2 * i]     * bu2f((unsigned short)(pr & 0xFFFFu));
      acc += wr[2 * i + 1] * bu2f((unsigned short)(pr >> 16));
    }
    off[((b * 18 + o) * HO_ + ho) * WO_ + wo] = acc;
  }
}

// --- K2 v9 "fused, depth-2 gather, SAFE A-schedule" (round-9 verified,
// 67.7us): sampling + full-K MFMA GEMM + BN stats. A-stage depth-2 over
// 3 buffers; gather depth-2 via two named register sets; steady vmcnt(8).
// Block = 256ch x 64px, 400 blocks, 4 waves, acc[8][2], 74 KB LDS.
__global__ __launch_bounds__(256) void k_fused(const unsigned short* __restrict__ Apk,
                                               const unsigned short* __restrict__ xcl,
                                               const float* __restrict__ off,
                                               float* __restrict__ out,
                                               float* __restrict__ accum) {
  __shared__ __align__(16) unsigned short a_sh[3][8192];  // 48 KB: 256ch x 32k x3
  __shared__ __align__(16) unsigned short b_sh[2][2048];  // 8 KB:  64px x 32k x2
  __shared__ __align__(16) int   pidx4[576][4];           // 9.2 KB corner idx
  __shared__ __align__(16) float pw4[576][4];             // 9.2 KB corner wts

  const int tid = threadIdx.x;
  const int wv = tid >> 6;
  const int ln = tid & 63;
  const int lm = ln & 15;
  const int qd = ln >> 4;
  const int wch = wv & 1;              // channel half (2)
  const int wpx = wv >> 1;             // pixel half (2)

  const int bid = blockIdx.x;          // 0..399
  const int xcd = bid & 7;
  const int T   = bid >> 3;            // 0..49
  const int b   = xcd + 8 * (T / 25);  // b%8 == xcd: matches k_cl L2 affinity
  const int tl  = T % 25;              // 64-px tile within batch (25*64=1600)

  // ---- meta: 64 px x 9 kk -> 4 corner offsets (abs elem idx) + 4 weights
  for (int j = tid; j < 576; j += 256) {
    int ipx = j / 9, kk = j - ipx * 9;
    int g  = tl * 64 + ipx;            // pixel within batch, 0..1599
    int ho = g / 40, wo = g - ho * 40;
    float dy = off[((b * 18 + 2 * kk) * HO_ + ho) * WO_ + wo];
    float dx = off[((b * 18 + 2 * kk + 1) * HO_ + ho) * WO_ + wo];
    float py  = (float)(2 * ho - 1 + (kk / 3)) + dy;
    float pxf = (float)(2 * wo - 1 + (kk % 3)) + dx;
    float y0f = floorf(py), x0f = floorf(pxf);
    float wy1 = py - y0f, wx1 = pxf - x0f;
    float wy0 = 1.f - wy1, wx0 = 1.f - wx1;
    int y0 = (int)y0f, x0 = (int)x0f;
    int y1 = y0 + 1, x1 = x0 + 1;
    bool vy0 = (y0 >= 0) && (y0 < H_), vy1 = (y1 >= 0) && (y1 < H_);
    bool vx0 = (x0 >= 0) && (x0 < W_), vx1 = (x1 >= 0) && (x1 < W_);
    int y0c = min(max(y0, 0), H_ - 1), y1c = min(max(y1, 0), H_ - 1);
    int x0c = min(max(x0, 0), W_ - 1), x1c = min(max(x1, 0), W_ - 1);
    int base = b * (H_ * W_ * CIN_);
    pidx4[j][0] = base + (y0c * W_ + x0c) * CIN_;  pw4[j][0] = (vy0 && vx0) ? wy0 * wx0 : 0.f;
    pidx4[j][1] = base + (y0c * W_ + x1c) * CIN_;  pw4[j][1] = (vy0 && vx1) ? wy0 * wx1 : 0.f;
    pidx4[j][2] = base + (y1c * W_ + x0c) * CIN_;  pw4[j][2] = (vy1 && vx0) ? wy1 * wx0 : 0.f;
    pidx4[j][3] = base + (y1c * W_ + x1c) * CIN_;  pw4[j][3] = (vy1 && vx1) ? wy1 * wx1 : 0.f;
  }
  __syncthreads();

#define STAGE_A(t, bf) do {                                                    \
    const unsigned short* s_ = Apk + (size_t)(t) * 8192 + wv * 2048 + ln * 8;  \
    gl_lds16(s_ + 0 * 512, &a_sh[bf][wv * 2048 + 0 * 512]);                    \
    gl_lds16(s_ + 1 * 512, &a_sh[bf][wv * 2048 + 1 * 512]);                    \
    gl_lds16(s_ + 2 * 512, &a_sh[bf][wv * 2048 + 2 * 512]);                    \
    gl_lds16(s_ + 3 * 512, &a_sh[bf][wv * 2048 + 3 * 512]);                    \
  } while (0)

// wave wv gathers the B granule-set for pt-group wv: lane (qd,lm) -> px lm,
// channels (t&3)*32 + qd*8 .. +8 of kernel tap t>>2 (old sampler contract).
#define GATHER(t, I_, W_, c00_, c01_, c10_, c11_) do {                         \
    int kk_ = (t) >> 2, ci0_ = ((t) & 3) * 32;                                 \
    int mi_ = ((wv << 4) + lm) * 9 + kk_;                                      \
    I_ = *(const int4*)&pidx4[mi_][0];                                         \
    W_ = *(const float4*)&pw4[mi_][0];                                         \
    int co_ = ci0_ + qd * 8;                                                   \
    c00_ = *(const short8*)(xcl + I_.x + co_);                                 \
    c01_ = *(const short8*)(xcl + I_.y + co_);                                 \
    c10_ = *(const short8*)(xcl + I_.z + co_);                                 \
    c11_ = *(const short8*)(xcl + I_.w + co_);                                 \
  } while (0)

// one K-step: wait for this step's data, blend, publish B, prefetch
// G(t+2) into the SAME named set, STAGE_A(t+2) into buffer (t+2)%3, MFMA.
#define BODY(t, I_, W_, c00_, c01_, c10_, c11_) do {                           \
    if ((t) == NKS_ - 1) asm volatile("s_waitcnt vmcnt(0)" ::: "memory");      \
    else                 asm volatile("s_waitcnt vmcnt(8)" ::: "memory");      \
    short8 rb;                                                                 \
    _Pragma("unroll")                                                          \
    for (int i2 = 0; i2 < 8; i2++) {                                           \
      float v = W_.x * bu2f((unsigned short)c00_[i2]) +                        \
                W_.y * bu2f((unsigned short)c01_[i2]) +                        \
                W_.z * bu2f((unsigned short)c10_[i2]) +                        \
                W_.w * bu2f((unsigned short)c11_[i2]);                         \
      rb[i2] = (short)f2bu(v);                                                 \
    }                                                                          \
    *(short8*)&b_sh[(t) & 1][wv * 512 + ln * 8] = rb;                          \
    asm volatile("s_waitcnt lgkmcnt(0)" ::: "memory");                         \
    __builtin_amdgcn_s_barrier();                                              \
    if ((t) + 2 < NKS_) {                                                      \
      GATHER((t) + 2, I_, W_, c00_, c01_, c10_, c11_);                         \
      STAGE_A((t) + 2, ((t) + 2) % 3);                                         \
    }                                                                          \
    const unsigned short* al = &a_sh[(t) % 3][abase];                          \
    const unsigned short* bl = &b_sh[(t) & 1][bbase];                          \
    short8 av[8], bv[2];                                                       \
    _Pragma("unroll")                                                          \
    for (int mt = 0; mt < 8; mt++) av[mt] = *(const short8*)(al + mt * 512);   \
    _Pragma("unroll")                                                          \
    for (int nt = 0; nt < 2; nt++) bv[nt] = *(const short8*)(bl + nt * 512);   \
    _Pragma("unroll")                                                          \
    for (int mt = 0; mt < 8; mt++)                                             \
      _Pragma("unroll")                                                        \
      for (int nt = 0; nt < 2; nt++)                                           \
        acc[mt][nt] = __builtin_amdgcn_mfma_f32_16x16x32_bf16(av[mt], bv[nt],  \
                                                              acc[mt][nt],     \
                                                              0, 0, 0);        \
  } while (0)

  floatx4 acc[8][2];
#pragma unroll
  for (int mt = 0; mt < 8; mt++)
#pragma unroll
    for (int nt = 0; nt < 2; nt++) acc[mt][nt] = (floatx4){0.f, 0.f, 0.f, 0.f};

  // two named gather sets (rule #20: static register naming, no runtime idx)
  int4 eI, oI; float4 eW, oW;
  short8 e00, e01, e10, e11, o00, o01, o10, o11;
  const int slot  = (qd + (lm >> 1)) & 3;               // A bank rotation
  const int abase = (wch * 128 + lm) * 32 + slot * 8;   // + mt*512
  const int bbase = (wpx * 2) * 512 + ln * 8;           // + nt*512

  // prologue issue order (vmcnt accounting): A0, G0, A1, G1  (16 outstanding)
  STAGE_A(0, 0);
  GATHER(0, eI, eW, e00, e01, e10, e11);
  STAGE_A(1, 1);
  GATHER(1, oI, oW, o00, o01, o10, o11);

#pragma unroll 1
  for (int t = 0; t < NKS_; t += 2) {
    BODY(t,     eI, eW, e00, e01, e10, e11);
    BODY(t + 1, oI, oW, o00, o01, o10, o11);
  }
#undef STAGE_A
#undef GATHER
#undef BODY

  // ---- C write: c = wch*128 + mt*16 + qd*4 + r; px = b*1600 + tl*64 + ...
  const int cb0 = wch * 128;
  float* ob = out + (size_t)b * COUT_ * 1600;
#pragma unroll
  for (int nt = 0; nt < 2; nt++) {
    const int rem = tl * 64 + (wpx * 2 + nt) * 16 + lm;
#pragma unroll
    for (int mt = 0; mt < 8; mt++) {
#pragma unroll
      for (int r = 0; r < 4; r++)
        ob[(size_t)(cb0 + mt * 16 + qd * 4 + r) * 1600 + rem] = acc[mt][nt][r];
    }
  }

  // ---- fused BN stats over this block's 64 px, all 256 ch
  __syncthreads();                      // a_sh dead; reuse as reduction buffer
  float* red = (float*)&a_sh[0][0];     // 512 floats: s1[256], s2[256]
  if (tid < 256) { red[tid] = 0.f; red[256 + tid] = 0.f; }
  __syncthreads();
#pragma unroll
  for (int mt = 0; mt < 8; mt++) {
#pragma unroll
    for (int r = 0; r < 4; r++) {
      float s = acc[mt][0][r] + acc[mt][1][r];
      float q = acc[mt][0][r] * acc[mt][0][r] + acc[mt][1][r] * acc[mt][1][r];
#pragma unroll
      for (int d = 1; d < 16; d <<= 1) {
        s += __shfl_xor(s, d, 16);
        q += __shfl_xor(q, d, 16);
      }
      if (lm == 0) {
        int lc = cb0 + mt * 16 + qd * 4 + r;
        atomicAdd(&red[lc], s);
        atomicAdd(&red[256 + lc], q);
      }
    }
  }
  __syncthreads();
  if (tid < 256) {
    atomicAdd(&accum[tid],         red[tid]);
    atomicAdd(&accum[COUT_ + tid], red[256 + tid]);
  }
}

// --------------------------- K3: BN + SiLU in place on the final out buffer
__global__ __launch_bounds__(256) void k_bn(float* __restrict__ io0,
                                            const float* __restrict__ accum,
                                            const float* __restrict__ gamma,
                                            const float* __restrict__ beta) {
  const int t = blockIdx.x * 256 + threadIdx.x;
  const int i0 = t * 4;
  const int c = (i0 / (HO_ * WO_)) % COUT_;
  const float mean = accum[c] * (1.f / NPIX_);
  const float var  = accum[COUT_ + c] * (1.f / NPIX_) - mean * mean;
  const float inv  = rsqrtf(var + 1e-5f);
  const float g  = gamma[c] * inv;
  const float be = beta[c] - mean * g;
  float4 r0 = *(const float4*)(io0 + i0);
  float v[4] = {r0.x, r0.y, r0.z, r0.w};
#pragma unroll
  for (int q = 0; q < 4; q++) {
    float u = v[q] * g + be;
    v[q] = u / (1.f + expf(-u));
  }
  *(float4*)(io0 + i0) = make_float4(v[0], v[1], v[2], v[3]);
}

// ----------------------------------------------------------------- launcher
extern "C" void kernel_launch(void* const* d_in, const int* in_sizes, int n_in,
                              void* d_out, int out_size, void* d_ws, size_t ws_size,
                              hipStream_t stream) {
  const float* x     = (const float*)d_in[0];
  const float* ow    = (const float*)d_in[1];
  const float* ob    = (const float*)d_in[2];
  const float* dw    = (const float*)d_in[3];
  const float* gamma = (const float*)d_in[5];
  const float* beta  = (const float*)d_in[6];
  float* out = (float*)d_out;

  float* off   = (float*)d_ws;                                 // 460800 f
  float* accum = off + B_ * 18 * HO_ * WO_;                    // 512 f
  unsigned short* Apk = (unsigned short*)(accum + 2 * COUT_);  // 294912 us
  unsigned short* xcl = Apk + (size_t)SK_ * COUT_;             // 13107200 us

  k_pack<<<SK_, 256, 0, stream>>>(dw, Apk, accum);
  k_cl<<<B_ * H_, 256, 0, stream>>>(x, xcl);
  k_off<<<B_ * HO_, 256, 0, stream>>>(xcl, ow, ob, off);
  k_fused<<<400, 256, 0, stream>>>(Apk, xcl, off, out, accum);
  k_bn<<<(NPIX_ * COUT_ / 4 + 255) / 256, 256, 0, stream>>>(
      out, accum, gamma, beta);
}

// Round 11
// 179.985 us; speedup vs baseline: 1.0730x; 1.0580x over previous
//
#include <hip/hip_runtime.h>
#include <hip/hip_bf16.h>

#define B_    16
#define CIN_  128
#define COUT_ 256
#define H_    80
#define W_    80
#define HO_   40
#define WO_   40
#define KK_   9
#define SK_   1152      // CIN_*KK_
#define NPIX_ 25600     // B_*HO_*WO_
#define NKS_  36        // K / 32

typedef __attribute__((ext_vector_type(8))) short short8;
typedef __attribute__((ext_vector_type(4))) float floatx4;

__device__ __forceinline__ unsigned short f2bu(float v) {
  __hip_bfloat16 h = __float2bfloat16(v);
  return *reinterpret_cast<unsigned short*>(&h);
}
__device__ __forceinline__ float bu2f(unsigned short u) {
  return __uint_as_float(((unsigned)u) << 16);
}
__device__ __forceinline__ unsigned int pk2(float a, float b) {
  return (unsigned)f2bu(a) | ((unsigned)f2bu(b) << 16);
}
// async global->LDS DMA, 16B per lane. LDS dest = wave-uniform base + lane*16.
__device__ __forceinline__ void gl_lds16(const unsigned short* g, unsigned short* l) {
  __builtin_amdgcn_global_load_lds(
      (const __attribute__((address_space(1))) unsigned int*)(const void*)g,
      (__attribute__((address_space(3))) unsigned int*)(void*)l, 16, 0, 0);
}

// ---------- K1 "clpack": merged k_cl + k_pack (disjoint block ranges).
// Blocks 0..1279: x -> channels-last bf16 + fused offset conv (round-2
// verified k_cl v2). Blocks 1280..1315: weight pack (round-2 verified v3
// layout Apk[ks(36)][cq(2)][mh(128)][slot(4)][j(8)], slot of row mh holds
// k-quad qd=(slot-(mh>>1))&3 -> conflict-free ds_read_b128; also zeroes the
// BN accumulators, replacing the memset dispatch).
__global__ __launch_bounds__(256) void k_clpack(const float* __restrict__ x,
                                                const float* __restrict__ ow,
                                                const float* __restrict__ ob,
                                                const float* __restrict__ dw,
                                                unsigned short* __restrict__ xcl,
                                                float* __restrict__ off,
                                                unsigned short* __restrict__ Apk,
                                                float* __restrict__ accum) {
  const int tid = threadIdx.x;
  const int bid = blockIdx.x;

  if (bid >= B_ * H_) {                       // ---- pack path (36 blocks)
    int t = (bid - B_ * H_) * 256 + tid;      // 0..9215 per... 36*256=9216? no:
    // 36 blocks x 256 = 9216 threads; need 294912 elems -> each does 32.
    if (t < 2 * COUT_) accum[t] = 0.f;
#pragma unroll
    for (int u = 0; u < 32; u++) {
      int e  = t * 32 + u;                    // 0..294911
      int j  = e & 7;
      int sl = (e >> 3) & 3;
      int mh = (e >> 5) & 127;
      int cq = (e >> 12) & 1;
      int ks = e >> 13;
      int qd = (sl - (mh >> 1)) & 3;
      int m  = cq * 128 + mh;
      int k  = ks * 32 + qd * 8 + j;
      int kk = k >> 7, ci = k & 127;
      Apk[e] = f2bu(dw[m * SK_ + ci * KK_ + kk]);
    }
    return;
  }

  // ---- channels-last path (1280 blocks), round-2 verified
  __shared__ unsigned int ts[CIN_ * 41];   // 21 KB: word xw holds x=2xw (lo), 2xw+1 (hi)
  __shared__ float owl[18 * CIN_];         // 9.2 KB
  __shared__ float obl[18];
  const int xcd = bid & 7;
  const int i0_ = bid >> 3;                // 0..159
  const int b   = (i0_ / 80) * 8 + xcd;
  const int y   = i0_ % 80;
  const bool even = (y & 1) == 0;

  // phase 1: coalesced float4 read along x, packed bf16 write into LDS
  for (int j = tid; j < CIN_ * 20; j += 256) {
    int ci = j / 20, xq = j % 20;
    float4 v = *(const float4*)&x[(((size_t)b * CIN_ + ci) * H_ + y) * W_ + xq * 4];
    ts[ci * 41 + xq * 2 + 0] = pk2(v.x, v.y);
    ts[ci * 41 + xq * 2 + 1] = pk2(v.z, v.w);
  }
  if (even) {
    for (int j = tid; j < 18 * CIN_; j += 256) owl[j] = ow[j];
    if (tid < 18) obl[tid] = ob[tid];
  }
  __syncthreads();

  // phase 2: transpose out of LDS; global stores 256B-contiguous per 32 lanes
  unsigned short* op = xcl + ((size_t)b * H_ * W_ + (size_t)y * W_) * CIN_;
  for (int j = tid; j < 40 * 32; j += 256) {
    int xw = j >> 5, cg = j & 31;          // xw = x-pair, cg = 4-channel group
    unsigned w0 = ts[(cg * 4 + 0) * 41 + xw];
    unsigned w1 = ts[(cg * 4 + 1) * 41 + xw];
    unsigned w2 = ts[(cg * 4 + 2) * 41 + xw];
    unsigned w3 = ts[(cg * 4 + 3) * 41 + xw];
    uint2 lo = make_uint2((w0 & 0xFFFFu) | (w1 << 16),
                          (w2 & 0xFFFFu) | (w3 << 16));
    uint2 hi = make_uint2((w0 >> 16) | (w1 & 0xFFFF0000u),
                          (w2 >> 16) | (w3 & 0xFFFF0000u));
    *(uint2*)(op + (size_t)(2 * xw) * CIN_ + cg * 4)     = lo;
    *(uint2*)(op + (size_t)(2 * xw + 1) * CIN_ + cg * 4) = hi;
  }

  // fused offset conv (even y): x at even positions = low half of word wo
  if (even) {
    const int ho = y >> 1;
    for (int i = tid; i < 18 * WO_; i += 256) {
      int o = i / WO_, wo = i - o * WO_;
      float acc = obl[o];
      const float* wr = &owl[o * CIN_];
#pragma unroll 4
      for (int ci = 0; ci < CIN_; ci++)
        acc += wr[ci] * bu2f((unsigned short)(ts[ci * 41 + wo] & 0xFFFFu));
      off[((b * 18 + o) * HO_ + ho) * WO_ + wo] = acc;
    }
  }
}

// ------------------------------------------ K2a: sampling from channels-last
// (round-2 verified) XCD-swizzled by b; coalesced 16B corner loads.
// Spk granule index is lm*4 + ((qd + (lm>>1)) & 3) (bank-rotated rows,
// matching k_gemm's rotated B-fragment read — both-sides-consistent).
__global__ __launch_bounds__(256) void k_sample_cl(const unsigned short* __restrict__ xcl,
                                                   const float* __restrict__ off,
                                                   unsigned short* __restrict__ Spk) {
  __shared__ __align__(16) int   pidx[80 * 4];
  __shared__ __align__(16) float pw[80 * 4];
  const int tid = threadIdx.x;
  const int j0   = blockIdx.x;         // 0..2879
  const int xcd  = j0 & 7;
  const int s    = j0 >> 3;
  const int b_hi = s / 180;
  const int t0   = s % 180;
  const int g    = t0 / 9;
  const int kk   = t0 % 9;
  const int b    = b_hi * 8 + xcd;
  const int ho0  = g * 2;

  if (tid < 80) {
    int hop = tid / 40, px = tid % 40;
    int ho = ho0 + hop;
    float dy = off[((b * 18 + 2 * kk) * HO_ + ho) * WO_ + px];
    float dx = off[((b * 18 + 2 * kk + 1) * HO_ + ho) * WO_ + px];
    float py  = (float)(2 * ho - 1 + (kk / 3)) + dy;
    float pxf = (float)(2 * px - 1 + (kk % 3)) + dx;
    float y0f = floorf(py), x0f = floorf(pxf);
    float wy1 = py - y0f, wx1 = pxf - x0f;
    float wy0 = 1.f - wy1, wx0 = 1.f - wx1;
    int y0 = (int)y0f, x0 = (int)x0f;
    int y1 = y0 + 1, x1 = x0 + 1;
    bool vy0 = (y0 >= 0) && (y0 < H_);
    bool vy1 = (y1 >= 0) && (y1 < H_);
    bool vx0 = (x0 >= 0) && (x0 < W_);
    bool vx1 = (x1 >= 0) && (x1 < W_);
    int y0c = min(max(y0, 0), H_ - 1), y1c = min(max(y1, 0), H_ - 1);
    int x0c = min(max(x0, 0), W_ - 1), x1c = min(max(x1, 0), W_ - 1);
    pidx[tid * 4 + 0] = (y0c * W_ + x0c) << 7;  pw[tid * 4 + 0] = (vy0 && vx0) ? wy0 * wx0 : 0.f;
    pidx[tid * 4 + 1] = (y0c * W_ + x1c) << 7;  pw[tid * 4 + 1] = (vy0 && vx1) ? wy0 * wx1 : 0.f;
    pidx[tid * 4 + 2] = (y1c * W_ + x0c) << 7;  pw[tid * 4 + 2] = (vy1 && vx0) ? wy1 * wx0 : 0.f;
    pidx[tid * 4 + 3] = (y1c * W_ + x1c) << 7;  pw[tid * 4 + 3] = (vy1 && vx1) ? wy1 * wx1 : 0.f;
  }
  __syncthreads();

  const unsigned short* xb = xcl + (size_t)b * (H_ * W_ * CIN_);
#pragma unroll
  for (int it = 0; it < 5; it++) {
    int i = it * 256 + tid;            // (pxh, oct), oct fastest
    int oct = i & 15;
    int pxh = i >> 4;                  // 0..79
    int4   I  = *(const int4*)&pidx[pxh * 4];
    float4 Wv = *(const float4*)&pw[pxh * 4];
    short8 c00 = *(const short8*)(xb + I.x + oct * 8);
    short8 c01 = *(const short8*)(xb + I.y + oct * 8);
    short8 c10 = *(const short8*)(xb + I.z + oct * 8);
    short8 c11 = *(const short8*)(xb + I.w + oct * 8);
    short8 r;
#pragma unroll
    for (int i2 = 0; i2 < 8; i2++) {
      float v = Wv.x * bu2f((unsigned short)c00[i2]) +
                Wv.y * bu2f((unsigned short)c01[i2]) +
                Wv.z * bu2f((unsigned short)c10[i2]) +
                Wv.w * bu2f((unsigned short)c11[i2]);
      r[i2] = (short)f2bu(v);
    }
    int p  = b * 1600 + (ho0 + (pxh / 40)) * 40 + (pxh % 40);
    int pt = p >> 4, lm = p & 15;
    int ks = kk * 4 + (oct >> 2);
    int qd = oct & 3;
    int gr = lm * 4 + ((qd + (lm >> 1)) & 3);   // bank-rotated granule
    *(short8*)&Spk[(((size_t)pt * NKS_ + ks) * 64 + gr) * 8] = r;
  }
}

// --- K2b: round-2 verified GEMM (best measured: 40.5us, total 185.45us).
// Full-K, 128ch x 128px per block, 2x2 waves of 64x64: 16 MFMA from
// 8 ds_read_b128 per wave-step (0.5 KB LDS/MFMA). 3-buffer LDS (48 KB),
// counted-vmcnt pipeline (steady vmcnt(4), never drains to 0 mid-loop),
// rotated A + rotated B layouts (0 bank conflicts), fused BN stats.
// 400 blocks, cq pairs adjacent on the same XCD (B L2 reuse).
__global__ __launch_bounds__(256) void k_gemm(const unsigned short* __restrict__ Apk,
                                              const unsigned short* __restrict__ Spk,
                                              float* __restrict__ out,
                                              float* __restrict__ accum) {
  __shared__ __align__(16) unsigned short a_sh[3][4096];  // 24 KB: 128ch x 32k x3
  __shared__ __align__(16) unsigned short b_sh[3][4096];  // 24 KB: 128px x 32k x3

  const int tid = threadIdx.x;
  const int wv = tid >> 6;
  const int ln = tid & 63;
  const int lm = ln & 15;
  const int qd = ln >> 4;
  const int wch = wv & 1;              // channel wave (2)
  const int wpx = wv >> 1;             // pixel wave (2)

  const int bid = blockIdx.x;          // 0..399
  const int xcd = bid & 7;
  const int cq  = (bid >> 3) & 1;      // channel half (adjacent bids pair on XCD)
  const int T   = bid >> 4;            // 0..24
  const int tile = T * 8 + xcd;        // px tile 0..199
  const int pt0 = tile * 8;            // 8 pt-groups = 128 px

  // per-step global slices
  const unsigned short* ag = Apk + (size_t)cq * 4096 + (wv * 2) * 512 + ln * 8;
  const unsigned short* bg0 = Spk + ((size_t)(pt0 + wv * 2 + 0) * NKS_) * 512 + ln * 8;
  const unsigned short* bg1 = Spk + ((size_t)(pt0 + wv * 2 + 1) * NKS_) * 512 + ln * 8;

#define STAGE(t, bf) do {                                                  \
    gl_lds16(ag + (size_t)(t) * 8192,       &a_sh[bf][(wv * 2 + 0) * 512]);\
    gl_lds16(ag + (size_t)(t) * 8192 + 512, &a_sh[bf][(wv * 2 + 1) * 512]);\
    gl_lds16(bg0 + (size_t)(t) * 512,       &b_sh[bf][(wv * 2 + 0) * 512]);\
    gl_lds16(bg1 + (size_t)(t) * 512,       &b_sh[bf][(wv * 2 + 1) * 512]);\
  } while (0)

  floatx4 acc[4][4];
#pragma unroll
  for (int mt = 0; mt < 4; mt++)
#pragma unroll
    for (int nt = 0; nt < 4; nt++) acc[mt][nt] = (floatx4){0.f, 0.f, 0.f, 0.f};

  const int slot = (qd + (lm >> 1)) & 3;               // bank rotation
  const int aoff0 = (wch * 64 + lm) * 32 + slot * 8;   // + mt*512
  const int boff0 = (wpx * 4) * 512 + lm * 32 + slot * 8;  // + nt*512 (rotated)

  STAGE(0, 0);
  STAGE(1, 1);
  asm volatile("s_waitcnt vmcnt(4)" ::: "memory");     // t0 landed, t1 in flight
  __builtin_amdgcn_s_barrier();

#pragma unroll 1
  for (int ks = 0; ks < NKS_; ks++) {
    const int bcur = ks % 3;
    if (ks + 2 < NKS_) STAGE(ks + 2, (ks + 2) % 3);

    short8 av[4], bv[4];
#pragma unroll
    for (int mt = 0; mt < 4; mt++)
      av[mt] = *(const short8*)(&a_sh[bcur][aoff0 + mt * 512]);
#pragma unroll
    for (int nt = 0; nt < 4; nt++)
      bv[nt] = *(const short8*)(&b_sh[bcur][boff0 + nt * 512]);
#pragma unroll
    for (int mt = 0; mt < 4; mt++)
#pragma unroll
      for (int nt = 0; nt < 4; nt++)
        acc[mt][nt] = __builtin_amdgcn_mfma_f32_16x16x32_bf16(av[mt], bv[nt],
                                                              acc[mt][nt], 0, 0, 0);
    if (ks + 1 < NKS_) {
      if (ks < NKS_ - 2) asm volatile("s_waitcnt vmcnt(4)" ::: "memory");
      else               asm volatile("s_waitcnt vmcnt(0)" ::: "memory");
      __builtin_amdgcn_s_barrier();
    }
  }
#undef STAGE

  // ---- C write: c = cq*128 + wch*64 + mt*16 + qd*4 + r; px = (pt0+wpx*4+nt)*16+lm
  const int cb0 = cq * 128 + wch * 64;
#pragma unroll
  for (int nt = 0; nt < 4; nt++) {
    const int p = (pt0 + wpx * 4 + nt) * 16 + lm;
    const int bb = p / 1600, rem = p - bb * 1600;
    float* ob = out + (size_t)bb * COUT_ * 1600 + rem;
#pragma unroll
    for (int mt = 0; mt < 4; mt++) {
#pragma unroll
      for (int r = 0; r < 4; r++)
        ob[(size_t)(cb0 + mt * 16 + qd * 4 + r) * 1600] = acc[mt][nt][r];
    }
  }

  // ---- fused BN stats: sum/sq-sum over this block's 128 px per channel.
  __syncthreads();                      // a_sh dead; reuse as reduction buffer
  float* red = (float*)&a_sh[0][0];     // 256 floats: s1[128], s2[128]
  red[tid & 255] = 0.f;
  __syncthreads();
#pragma unroll
  for (int mt = 0; mt < 4; mt++) {
#pragma unroll
    for (int r = 0; r < 4; r++) {
      float s = acc[mt][0][r] + acc[mt][1][r] + acc[mt][2][r] + acc[mt][3][r];
      float q = acc[mt][0][r] * acc[mt][0][r] + acc[mt][1][r] * acc[mt][1][r] +
                acc[mt][2][r] * acc[mt][2][r] + acc[mt][3][r] * acc[mt][3][r];
#pragma unroll
      for (int d = 1; d < 16; d <<= 1) {
        s += __shfl_xor(s, d, 16);
        q += __shfl_xor(q, d, 16);
      }
      if (lm == 0) {
        int lc = wch * 64 + mt * 16 + qd * 4 + r;
        atomicAdd(&red[lc], s);
        atomicAdd(&red[128 + lc], q);
      }
    }
  }
  __syncthreads();
  if (tid < 128) {
    atomicAdd(&accum[cq * 128 + tid],         red[tid]);
    atomicAdd(&accum[COUT_ + cq * 128 + tid], red[128 + tid]);
  }
}

// --------------------------- K3: BN + SiLU in place on the final out buffer
__global__ __launch_bounds__(256) void k_bn(float* __restrict__ io0,
                                            const float* __restrict__ accum,
                                            const float* __restrict__ gamma,
                                            const float* __restrict__ beta) {
  const int t = blockIdx.x * 256 + threadIdx.x;
  const int i0 = t * 4;
  const int c = (i0 / (HO_ * WO_)) % COUT_;
  const float mean = accum[c] * (1.f / NPIX_);
  const float var  = accum[COUT_ + c] * (1.f / NPIX_) - mean * mean;
  const float inv  = rsqrtf(var + 1e-5f);
  const float g  = gamma[c] * inv;
  const float be = beta[c] - mean * g;
  float4 r0 = *(const float4*)(io0 + i0);
  float v[4] = {r0.x, r0.y, r0.z, r0.w};
#pragma unroll
  for (int q = 0; q < 4; q++) {
    float u = v[q] * g + be;
    v[q] = u / (1.f + expf(-u));
  }
  *(float4*)(io0 + i0) = make_float4(v[0], v[1], v[2], v[3]);
}

// ----------------------------------------------------------------- launcher
extern "C" void kernel_launch(void* const* d_in, const int* in_sizes, int n_in,
                              void* d_out, int out_size, void* d_ws, size_t ws_size,
                              hipStream_t stream) {
  const float* x     = (const float*)d_in[0];
  const float* ow    = (const float*)d_in[1];
  const float* ob    = (const float*)d_in[2];
  const float* dw    = (const float*)d_in[3];
  const float* gamma = (const float*)d_in[5];
  const float* beta  = (const float*)d_in[6];
  float* out = (float*)d_out;

  float* off   = (float*)d_ws;                                 // 460800 f
  float* accum = off + B_ * 18 * HO_ * WO_;                    // 512 f
  unsigned short* Apk = (unsigned short*)(accum + 2 * COUT_);  // 294912 us
  unsigned short* Spk = Apk + (size_t)SK_ * COUT_;             // 29491200 us
  unsigned short* xcl = Spk + (size_t)NPIX_ * SK_;             // 13107200 us

  k_clpack<<<B_ * H_ + 36, 256, 0, stream>>>(x, ow, ob, dw, xcl, off, Apk, accum);
  k_sample_cl<<<B_ * KK_ * 20, 256, 0, stream>>>(xcl, off, Spk);
  k_gemm<<<400, 256, 0, stream>>>(Apk, Spk, out, accum);
  k_bn<<<(NPIX_ * COUT_ / 4 + 255) / 256, 256, 0, stream>>>(
      out, accum, gamma, beta);
}

// Round 12
// 174.685 us; speedup vs baseline: 1.1056x; 1.0303x over previous
//
#include <hip/hip_runtime.h>
#include <hip/hip_bf16.h>

#define B_    16
#define CIN_  128
#define COUT_ 256
#define H_    80
#define W_    80
#define HO_   40
#define WO_   40
#define KK_   9
#define SK_   1152      // CIN_*KK_
#define NPIX_ 25600     // B_*HO_*WO_
#define NKS_  36        // K / 32

typedef __attribute__((ext_vector_type(8))) short short8;
typedef __attribute__((ext_vector_type(4))) float floatx4;

__device__ __forceinline__ unsigned short f2bu(float v) {
  __hip_bfloat16 h = __float2bfloat16(v);
  return *reinterpret_cast<unsigned short*>(&h);
}
__device__ __forceinline__ float bu2f(unsigned short u) {
  return __uint_as_float(((unsigned)u) << 16);
}
__device__ __forceinline__ unsigned int pk2(float a, float b) {
  return (unsigned)f2bu(a) | ((unsigned)f2bu(b) << 16);
}
// async global->LDS DMA, 16B per lane. LDS dest = wave-uniform base + lane*16.
__device__ __forceinline__ void gl_lds16(const unsigned short* g, unsigned short* l) {
  __builtin_amdgcn_global_load_lds(
      (const __attribute__((address_space(1))) unsigned int*)(const void*)g,
      (__attribute__((address_space(3))) unsigned int*)(void*)l, 16, 0, 0);
}

// ---------- K1 "clpack": merged k_cl + k_pack (disjoint block ranges).
// (round-11 verified, 180.0us total) Blocks 0..1279: x -> channels-last bf16
// + fused offset conv. Blocks 1280..1315: weight pack (v3 layout
// Apk[ks(36)][cq(2)][mh(128)][slot(4)][j(8)], slot of row mh holds k-quad
// qd=(slot-(mh>>1))&3) + zero BN accumulators.
__global__ __launch_bounds__(256) void k_clpack(const float* __restrict__ x,
                                                const float* __restrict__ ow,
                                                const float* __restrict__ ob,
                                                const float* __restrict__ dw,
                                                unsigned short* __restrict__ xcl,
                                                float* __restrict__ off,
                                                unsigned short* __restrict__ Apk,
                                                float* __restrict__ accum) {
  const int tid = threadIdx.x;
  const int bid = blockIdx.x;

  if (bid >= B_ * H_) {                       // ---- pack path (36 blocks)
    int t = (bid - B_ * H_) * 256 + tid;      // 0..9215; each thread packs 32
    if (t < 2 * COUT_) accum[t] = 0.f;
#pragma unroll
    for (int u = 0; u < 32; u++) {
      int e  = t * 32 + u;                    // 0..294911
      int j  = e & 7;
      int sl = (e >> 3) & 3;
      int mh = (e >> 5) & 127;
      int cq = (e >> 12) & 1;
      int ks = e >> 13;
      int qd = (sl - (mh >> 1)) & 3;
      int m  = cq * 128 + mh;
      int k  = ks * 32 + qd * 8 + j;
      int kk = k >> 7, ci = k & 127;
      Apk[e] = f2bu(dw[m * SK_ + ci * KK_ + kk]);
    }
    return;
  }

  // ---- channels-last path (1280 blocks), round-2 verified
  __shared__ unsigned int ts[CIN_ * 41];   // 21 KB: word xw holds x=2xw (lo), 2xw+1 (hi)
  __shared__ float owl[18 * CIN_];         // 9.2 KB
  __shared__ float obl[18];
  const int xcd = bid & 7;
  const int i0_ = bid >> 3;                // 0..159
  const int b   = (i0_ / 80) * 8 + xcd;
  const int y   = i0_ % 80;
  const bool even = (y & 1) == 0;

  // phase 1: coalesced float4 read along x, packed bf16 write into LDS
  for (int j = tid; j < CIN_ * 20; j += 256) {
    int ci = j / 20, xq = j % 20;
    float4 v = *(const float4*)&x[(((size_t)b * CIN_ + ci) * H_ + y) * W_ + xq * 4];
    ts[ci * 41 + xq * 2 + 0] = pk2(v.x, v.y);
    ts[ci * 41 + xq * 2 + 1] = pk2(v.z, v.w);
  }
  if (even) {
    for (int j = tid; j < 18 * CIN_; j += 256) owl[j] = ow[j];
    if (tid < 18) obl[tid] = ob[tid];
  }
  __syncthreads();

  // phase 2: transpose out of LDS; global stores 256B-contiguous per 32 lanes
  unsigned short* op = xcl + ((size_t)b * H_ * W_ + (size_t)y * W_) * CIN_;
  for (int j = tid; j < 40 * 32; j += 256) {
    int xw = j >> 5, cg = j & 31;          // xw = x-pair, cg = 4-channel group
    unsigned w0 = ts[(cg * 4 + 0) * 41 + xw];
    unsigned w1 = ts[(cg * 4 + 1) * 41 + xw];
    unsigned w2 = ts[(cg * 4 + 2) * 41 + xw];
    unsigned w3 = ts[(cg * 4 + 3) * 41 + xw];
    uint2 lo = make_uint2((w0 & 0xFFFFu) | (w1 << 16),
                          (w2 & 0xFFFFu) | (w3 << 16));
    uint2 hi = make_uint2((w0 >> 16) | (w1 & 0xFFFF0000u),
                          (w2 >> 16) | (w3 & 0xFFFF0000u));
    *(uint2*)(op + (size_t)(2 * xw) * CIN_ + cg * 4)     = lo;
    *(uint2*)(op + (size_t)(2 * xw + 1) * CIN_ + cg * 4) = hi;
  }

  // fused offset conv (even y): x at even positions = low half of word wo
  if (even) {
    const int ho = y >> 1;
    for (int i = tid; i < 18 * WO_; i += 256) {
      int o = i / WO_, wo = i - o * WO_;
      float acc = obl[o];
      const float* wr = &owl[o * CIN_];
#pragma unroll 4
      for (int ci = 0; ci < CIN_; ci++)
        acc += wr[ci] * bu2f((unsigned short)(ts[ci * 41 + wo] & 0xFFFFu));
      off[((b * 18 + o) * HO_ + ho) * WO_ + wo] = acc;
    }
  }
}

// ------------------------------------------ K2a: sampling from channels-last
// (round-2 verified) XCD-swizzled by b; coalesced 16B corner loads.
// Spk granule index is lm*4 + ((qd + (lm>>1)) & 3) (bank-rotated rows,
// matching k_gemm's rotated B-fragment read — both-sides-consistent).
__global__ __launch_bounds__(256) void k_sample_cl(const unsigned short* __restrict__ xcl,
                                                   const float* __restrict__ off,
                                                   unsigned short* __restrict__ Spk) {
  __shared__ __align__(16) int   pidx[80 * 4];
  __shared__ __align__(16) float pw[80 * 4];
  const int tid = threadIdx.x;
  const int j0   = blockIdx.x;         // 0..2879
  const int xcd  = j0 & 7;
  const int s    = j0 >> 3;
  const int b_hi = s / 180;
  const int t0   = s % 180;
  const int g    = t0 / 9;
  const int kk   = t0 % 9;
  const int b    = b_hi * 8 + xcd;
  const int ho0  = g * 2;

  if (tid < 80) {
    int hop = tid / 40, px = tid % 40;
    int ho = ho0 + hop;
    float dy = off[((b * 18 + 2 * kk) * HO_ + ho) * WO_ + px];
    float dx = off[((b * 18 + 2 * kk + 1) * HO_ + ho) * WO_ + px];
    float py  = (float)(2 * ho - 1 + (kk / 3)) + dy;
    float pxf = (float)(2 * px - 1 + (kk % 3)) + dx;
    float y0f = floorf(py), x0f = floorf(pxf);
    float wy1 = py - y0f, wx1 = pxf - x0f;
    float wy0 = 1.f - wy1, wx0 = 1.f - wx1;
    int y0 = (int)y0f, x0 = (int)x0f;
    int y1 = y0 + 1, x1 = x0 + 1;
    bool vy0 = (y0 >= 0) && (y0 < H_);
    bool vy1 = (y1 >= 0) && (y1 < H_);
    bool vx0 = (x0 >= 0) && (x0 < W_);
    bool vx1 = (x1 >= 0) && (x1 < W_);
    int y0c = min(max(y0, 0), H_ - 1), y1c = min(max(y1, 0), H_ - 1);
    int x0c = min(max(x0, 0), W_ - 1), x1c = min(max(x1, 0), W_ - 1);
    pidx[tid * 4 + 0] = (y0c * W_ + x0c) << 7;  pw[tid * 4 + 0] = (vy0 && vx0) ? wy0 * wx0 : 0.f;
    pidx[tid * 4 + 1] = (y0c * W_ + x1c) << 7;  pw[tid * 4 + 1] = (vy0 && vx1) ? wy0 * wx1 : 0.f;
    pidx[tid * 4 + 2] = (y1c * W_ + x0c) << 7;  pw[tid * 4 + 2] = (vy1 && vx0) ? wy1 * wx0 : 0.f;
    pidx[tid * 4 + 3] = (y1c * W_ + x1c) << 7;  pw[tid * 4 + 3] = (vy1 && vx1) ? wy1 * wx1 : 0.f;
  }
  __syncthreads();

  const unsigned short* xb = xcl + (size_t)b * (H_ * W_ * CIN_);
#pragma unroll
  for (int it = 0; it < 5; it++) {
    int i = it * 256 + tid;            // (pxh, oct), oct fastest
    int oct = i & 15;
    int pxh = i >> 4;                  // 0..79
    int4   I  = *(const int4*)&pidx[pxh * 4];
    float4 Wv = *(const float4*)&pw[pxh * 4];
    short8 c00 = *(const short8*)(xb + I.x + oct * 8);
    short8 c01 = *(const short8*)(xb + I.y + oct * 8);
    short8 c10 = *(const short8*)(xb + I.z + oct * 8);
    short8 c11 = *(const short8*)(xb + I.w + oct * 8);
    short8 r;
#pragma unroll
    for (int i2 = 0; i2 < 8; i2++) {
      float v = Wv.x * bu2f((unsigned short)c00[i2]) +
                Wv.y * bu2f((unsigned short)c01[i2]) +
                Wv.z * bu2f((unsigned short)c10[i2]) +
                Wv.w * bu2f((unsigned short)c11[i2]);
      r[i2] = (short)f2bu(v);
    }
    int p  = b * 1600 + (ho0 + (pxh / 40)) * 40 + (pxh % 40);
    int pt = p >> 4, lm = p & 15;
    int ks = kk * 4 + (oct >> 2);
    int qd = oct & 3;
    int gr = lm * 4 + ((qd + (lm >> 1)) & 3);   // bank-rotated granule
    *(short8*)&Spk[(((size_t)pt * NKS_ + ks) * 64 + gr) * 8] = r;
  }
}

// --- K2b v10 "BK=64": round-11 structure (128ch x 128px, 2x2 waves of 64x64,
// rotated A+B, 400 blocks, cq pairs same-XCD) with TWO K-steps per barrier
// interval. 18 intervals (was 36): per interval one vmcnt(0)+barrier,
// 8 gl_lds (issued post-barrier, fly under compute), 16 ds_read_b128 +
// 32 MFMA per wave. Rationale: r2/r3/r6 showed per-interval cost is mostly
// FIXED overhead (~2200cyc) not content (~500cyc); halving intervals should
// approach 18x(overhead+2x content). LDS 2 x 32KB = 64KB -> 2 blocks/CU,
// all 400 co-resident. Buffer safety: stage(i+1) targets buf[(i+1)&1] and
// is issued only after barrier(i), which all waves reach after lgkmcnt(0)
// drained their reads of that buffer. Fused BN stats unchanged.
__global__ __launch_bounds__(256) void k_gemm(const unsigned short* __restrict__ Apk,
                                              const unsigned short* __restrict__ Spk,
                                              float* __restrict__ out,
                                              float* __restrict__ accum) {
  __shared__ __align__(16) unsigned short a_sh[2][8192];  // 32 KB: 128ch x 64k x2
  __shared__ __align__(16) unsigned short b_sh[2][8192];  // 32 KB: 128px x 64k x2

  const int tid = threadIdx.x;
  const int wv = tid >> 6;
  const int ln = tid & 63;
  const int lm = ln & 15;
  const int qd = ln >> 4;
  const int wch = wv & 1;              // channel wave (2)
  const int wpx = wv >> 1;             // pixel wave (2)

  const int bid = blockIdx.x;          // 0..399
  const int xcd = bid & 7;
  const int cq  = (bid >> 3) & 1;      // channel half (bid pair 8 apart -> same XCD)
  const int T   = bid >> 4;            // 0..24
  const int tile = T * 8 + xcd;        // px tile 0..199
  const int pt0 = tile * 8;            // 8 pt-groups = 128 px

  // per-k-step global slices (ks stride: A 8192 shorts, B 512 shorts)
  const unsigned short* ag = Apk + (size_t)cq * 4096 + (wv * 2) * 512 + ln * 8;
  const unsigned short* bg0 = Spk + ((size_t)(pt0 + wv * 2 + 0) * NKS_) * 512 + ln * 8;
  const unsigned short* bg1 = Spk + ((size_t)(pt0 + wv * 2 + 1) * NKS_) * 512 + ln * 8;

// stage interval i = k-steps 2i, 2i+1 into buffer bf (8 loads/wave)
#define STAGE2(i, bf) do {                                                        \
    gl_lds16(ag + (size_t)(2 * (i)) * 8192,           &a_sh[bf][(wv * 2 + 0) * 512]);        \
    gl_lds16(ag + (size_t)(2 * (i)) * 8192 + 512,     &a_sh[bf][(wv * 2 + 1) * 512]);        \
    gl_lds16(ag + (size_t)(2 * (i) + 1) * 8192,       &a_sh[bf][4096 + (wv * 2 + 0) * 512]); \
    gl_lds16(ag + (size_t)(2 * (i) + 1) * 8192 + 512, &a_sh[bf][4096 + (wv * 2 + 1) * 512]); \
    gl_lds16(bg0 + (size_t)(2 * (i)) * 512,           &b_sh[bf][(wv * 2 + 0) * 512]);        \
    gl_lds16(bg1 + (size_t)(2 * (i)) * 512,           &b_sh[bf][(wv * 2 + 1) * 512]);        \
    gl_lds16(bg0 + (size_t)(2 * (i) + 1) * 512,       &b_sh[bf][4096 + (wv * 2 + 0) * 512]); \
    gl_lds16(bg1 + (size_t)(2 * (i) + 1) * 512,       &b_sh[bf][4096 + (wv * 2 + 1) * 512]); \
  } while (0)

  floatx4 acc[4][4];
#pragma unroll
  for (int mt = 0; mt < 4; mt++)
#pragma unroll
    for (int nt = 0; nt < 4; nt++) acc[mt][nt] = (floatx4){0.f, 0.f, 0.f, 0.f};

  const int slot = (qd + (lm >> 1)) & 3;               // bank rotation
  const int aoff0 = (wch * 64 + lm) * 32 + slot * 8;   // + mt*512 (k-step 0 half)
  const int boff0 = (wpx * 4) * 512 + lm * 32 + slot * 8;  // + nt*512 (rotated)

  STAGE2(0, 0);

#pragma unroll 1
  for (int i = 0; i < 18; i++) {
    // stage(i) is the only outstanding batch here (stage(i+1) not yet issued)
    asm volatile("s_waitcnt vmcnt(0)" ::: "memory");
    __builtin_amdgcn_s_barrier();
    if (i + 1 < 18) STAGE2(i + 1, (i + 1) & 1);   // flies under compute below

    const unsigned short* al = &a_sh[i & 1][0];
    const unsigned short* bl = &b_sh[i & 1][0];
    short8 av[4], bv[4], av2[4], bv2[4];
#pragma unroll
    for (int mt = 0; mt < 4; mt++) {
      av[mt]  = *(const short8*)(al + aoff0 + mt * 512);
      av2[mt] = *(const short8*)(al + 4096 + aoff0 + mt * 512);
    }
#pragma unroll
    for (int nt = 0; nt < 4; nt++) {
      bv[nt]  = *(const short8*)(bl + boff0 + nt * 512);
      bv2[nt] = *(const short8*)(bl + 4096 + boff0 + nt * 512);
    }
#pragma unroll
    for (int mt = 0; mt < 4; mt++)
#pragma unroll
      for (int nt = 0; nt < 4; nt++)
        acc[mt][nt] = __builtin_amdgcn_mfma_f32_16x16x32_bf16(av[mt], bv[nt],
                                                              acc[mt][nt], 0, 0, 0);
#pragma unroll
    for (int mt = 0; mt < 4; mt++)
#pragma unroll
      for (int nt = 0; nt < 4; nt++)
        acc[mt][nt] = __builtin_amdgcn_mfma_f32_16x16x32_bf16(av2[mt], bv2[nt],
                                                              acc[mt][nt], 0, 0, 0);
    // all this wave's ds_reads of buf[i&1] retired before it can reach
    // barrier(i+1) and allow stage(i+2) to overwrite that buffer
    asm volatile("s_waitcnt lgkmcnt(0)" ::: "memory");
  }
#undef STAGE2

  // ---- C write: c = cq*128 + wch*64 + mt*16 + qd*4 + r; px = (pt0+wpx*4+nt)*16+lm
  const int cb0 = cq * 128 + wch * 64;
#pragma unroll
  for (int nt = 0; nt < 4; nt++) {
    const int p = (pt0 + wpx * 4 + nt) * 16 + lm;
    const int bb = p / 1600, rem = p - bb * 1600;
    float* ob = out + (size_t)bb * COUT_ * 1600 + rem;
#pragma unroll
    for (int mt = 0; mt < 4; mt++) {
#pragma unroll
      for (int r = 0; r < 4; r++)
        ob[(size_t)(cb0 + mt * 16 + qd * 4 + r) * 1600] = acc[mt][nt][r];
    }
  }

  // ---- fused BN stats: sum/sq-sum over this block's 128 px per channel.
  __syncthreads();                      // a_sh dead; reuse as reduction buffer
  float* red = (float*)&a_sh[0][0];     // 256 floats: s1[128], s2[128]
  red[tid & 255] = 0.f;
  __syncthreads();
#pragma unroll
  for (int mt = 0; mt < 4; mt++) {
#pragma unroll
    for (int r = 0; r < 4; r++) {
      float s = acc[mt][0][r] + acc[mt][1][r] + acc[mt][2][r] + acc[mt][3][r];
      float q = acc[mt][0][r] * acc[mt][0][r] + acc[mt][1][r] * acc[mt][1][r] +
                acc[mt][2][r] * acc[mt][2][r] + acc[mt][3][r] * acc[mt][3][r];
#pragma unroll
      for (int d = 1; d < 16; d <<= 1) {
        s += __shfl_xor(s, d, 16);
        q += __shfl_xor(q, d, 16);
      }
      if (lm == 0) {
        int lc = wch * 64 + mt * 16 + qd * 4 + r;
        atomicAdd(&red[lc], s);
        atomicAdd(&red[128 + lc], q);
      }
    }
  }
  __syncthreads();
  if (tid < 128) {
    atomicAdd(&accum[cq * 128 + tid],         red[tid]);
    atomicAdd(&accum[COUT_ + cq * 128 + tid], red[128 + tid]);
  }
}

// --------------------------- K3: BN + SiLU in place on the final out buffer
__global__ __launch_bounds__(256) void k_bn(float* __restrict__ io0,
                                            const float* __restrict__ accum,
                                            const float* __restrict__ gamma,
                                            const float* __restrict__ beta) {
  const int t = blockIdx.x * 256 + threadIdx.x;
  const int i0 = t * 4;
  const int c = (i0 / (HO_ * WO_)) % COUT_;
  const float mean = accum[c] * (1.f / NPIX_);
  const float var  = accum[COUT_ + c] * (1.f / NPIX_) - mean * mean;
  const float inv  = rsqrtf(var + 1e-5f);
  const float g  = gamma[c] * inv;
  const float be = beta[c] - mean * g;
  float4 r0 = *(const float4*)(io0 + i0);
  float v[4] = {r0.x, r0.y, r0.z, r0.w};
#pragma unroll
  for (int q = 0; q < 4; q++) {
    float u = v[q] * g + be;
    v[q] = u / (1.f + expf(-u));
  }
  *(float4*)(io0 + i0) = make_float4(v[0], v[1], v[2], v[3]);
}

// ----------------------------------------------------------------- launcher
extern "C" void kernel_launch(void* const* d_in, const int* in_sizes, int n_in,
                              void* d_out, int out_size, void* d_ws, size_t ws_size,
                              hipStream_t stream) {
  const float* x     = (const float*)d_in[0];
  const float* ow    = (const float*)d_in[1];
  const float* ob    = (const float*)d_in[2];
  const float* dw    = (const float*)d_in[3];
  const float* gamma = (const float*)d_in[5];
  const float* beta  = (const float*)d_in[6];
  float* out = (float*)d_out;

  float* off   = (float*)d_ws;                                 // 460800 f
  float* accum = off + B_ * 18 * HO_ * WO_;                    // 512 f
  unsigned short* Apk = (unsigned short*)(accum + 2 * COUT_);  // 294912 us
  unsigned short* Spk = Apk + (size_t)SK_ * COUT_;             // 29491200 us
  unsigned short* xcl = Spk + (size_t)NPIX_ * SK_;             // 13107200 us

  k_clpack<<<B_ * H_ + 36, 256, 0, stream>>>(x, ow, ob, dw, xcl, off, Apk, accum);
  k_sample_cl<<<B_ * KK_ * 20, 256, 0, stream>>>(xcl, off, Spk);
  k_gemm<<<400, 256, 0, stream>>>(Apk, Spk, out, accum);
  k_bn<<<(NPIX_ * COUT_ / 4 + 255) / 256, 256, 0, stream>>>(
      out, accum, gamma, beta);
}

// Round 13
// 173.561 us; speedup vs baseline: 1.1127x; 1.0065x over previous
//
#include <hip/hip_runtime.h>
#include <hip/hip_bf16.h>

#define B_    16
#define CIN_  128
#define COUT_ 256
#define H_    80
#define W_    80
#define HO_   40
#define WO_   40
#define KK_   9
#define SK_   1152      // CIN_*KK_
#define NPIX_ 25600     // B_*HO_*WO_
#define NKS_  36        // K / 32

typedef __attribute__((ext_vector_type(8))) short short8;
typedef __attribute__((ext_vector_type(4))) float floatx4;

__device__ __forceinline__ unsigned short f2bu(float v) {
  __hip_bfloat16 h = __float2bfloat16(v);
  return *reinterpret_cast<unsigned short*>(&h);
}
__device__ __forceinline__ float bu2f(unsigned short u) {
  return __uint_as_float(((unsigned)u) << 16);
}
__device__ __forceinline__ unsigned int pk2(float a, float b) {
  return (unsigned)f2bu(a) | ((unsigned)f2bu(b) << 16);
}
// async global->LDS DMA, 16B per lane. LDS dest = wave-uniform base + lane*16.
__device__ __forceinline__ void gl_lds16(const unsigned short* g, unsigned short* l) {
  __builtin_amdgcn_global_load_lds(
      (const __attribute__((address_space(1))) unsigned int*)(const void*)g,
      (__attribute__((address_space(3))) unsigned int*)(void*)l, 16, 0, 0);
}

// ---------- K1 "clpack": merged k_cl + k_pack (disjoint block ranges).
// (round-11 verified) Blocks 0..1279: x -> channels-last bf16 + fused offset
// conv. Blocks 1280..1315: weight pack (v3 layout
// Apk[ks(36)][cq(2)][mh(128)][slot(4)][j(8)], slot of row mh holds k-quad
// qd=(slot-(mh>>1))&3) + zero BN accumulators.
__global__ __launch_bounds__(256) void k_clpack(const float* __restrict__ x,
                                                const float* __restrict__ ow,
                                                const float* __restrict__ ob,
                                                const float* __restrict__ dw,
                                                unsigned short* __restrict__ xcl,
                                                float* __restrict__ off,
                                                unsigned short* __restrict__ Apk,
                                                float* __restrict__ accum) {
  const int tid = threadIdx.x;
  const int bid = blockIdx.x;

  if (bid >= B_ * H_) {                       // ---- pack path (36 blocks)
    int t = (bid - B_ * H_) * 256 + tid;      // 0..9215; each thread packs 32
    if (t < 2 * COUT_) accum[t] = 0.f;
#pragma unroll
    for (int u = 0; u < 32; u++) {
      int e  = t * 32 + u;                    // 0..294911
      int j  = e & 7;
      int sl = (e >> 3) & 3;
      int mh = (e >> 5) & 127;
      int cq = (e >> 12) & 1;
      int ks = e >> 13;
      int qd = (sl - (mh >> 1)) & 3;
      int m  = cq * 128 + mh;
      int k  = ks * 32 + qd * 8 + j;
      int kk = k >> 7, ci = k & 127;
      Apk[e] = f2bu(dw[m * SK_ + ci * KK_ + kk]);
    }
    return;
  }

  // ---- channels-last path (1280 blocks), round-2 verified
  __shared__ unsigned int ts[CIN_ * 41];   // 21 KB: word xw holds x=2xw (lo), 2xw+1 (hi)
  __shared__ float owl[18 * CIN_];         // 9.2 KB
  __shared__ float obl[18];
  const int xcd = bid & 7;
  const int i0_ = bid >> 3;                // 0..159
  const int b   = (i0_ / 80) * 8 + xcd;
  const int y   = i0_ % 80;
  const bool even = (y & 1) == 0;

  // phase 1: coalesced float4 read along x, packed bf16 write into LDS
  for (int j = tid; j < CIN_ * 20; j += 256) {
    int ci = j / 20, xq = j % 20;
    float4 v = *(const float4*)&x[(((size_t)b * CIN_ + ci) * H_ + y) * W_ + xq * 4];
    ts[ci * 41 + xq * 2 + 0] = pk2(v.x, v.y);
    ts[ci * 41 + xq * 2 + 1] = pk2(v.z, v.w);
  }
  if (even) {
    for (int j = tid; j < 18 * CIN_; j += 256) owl[j] = ow[j];
    if (tid < 18) obl[tid] = ob[tid];
  }
  __syncthreads();

  // phase 2: transpose out of LDS; global stores 256B-contiguous per 32 lanes
  unsigned short* op = xcl + ((size_t)b * H_ * W_ + (size_t)y * W_) * CIN_;
  for (int j = tid; j < 40 * 32; j += 256) {
    int xw = j >> 5, cg = j & 31;          // xw = x-pair, cg = 4-channel group
    unsigned w0 = ts[(cg * 4 + 0) * 41 + xw];
    unsigned w1 = ts[(cg * 4 + 1) * 41 + xw];
    unsigned w2 = ts[(cg * 4 + 2) * 41 + xw];
    unsigned w3 = ts[(cg * 4 + 3) * 41 + xw];
    uint2 lo = make_uint2((w0 & 0xFFFFu) | (w1 << 16),
                          (w2 & 0xFFFFu) | (w3 << 16));
    uint2 hi = make_uint2((w0 >> 16) | (w1 & 0xFFFF0000u),
                          (w2 >> 16) | (w3 & 0xFFFF0000u));
    *(uint2*)(op + (size_t)(2 * xw) * CIN_ + cg * 4)     = lo;
    *(uint2*)(op + (size_t)(2 * xw + 1) * CIN_ + cg * 4) = hi;
  }

  // fused offset conv (even y): x at even positions = low half of word wo
  if (even) {
    const int ho = y >> 1;
    for (int i = tid; i < 18 * WO_; i += 256) {
      int o = i / WO_, wo = i - o * WO_;
      float acc = obl[o];
      const float* wr = &owl[o * CIN_];
#pragma unroll 4
      for (int ci = 0; ci < CIN_; ci++)
        acc += wr[ci] * bu2f((unsigned short)(ts[ci * 41 + wo] & 0xFFFFu));
      off[((b * 18 + o) * HO_ + ho) * WO_ + wo] = acc;
    }
  }
}

// ------------------------------------------ K2a: sampling from channels-last
// (round-2 verified) XCD-swizzled by b; coalesced 16B corner loads.
// Spk granule index is lm*4 + ((qd + (lm>>1)) & 3) (bank-rotated rows,
// matching k_gemm's rotated B-fragment read — both-sides-consistent).
__global__ __launch_bounds__(256) void k_sample_cl(const unsigned short* __restrict__ xcl,
                                                   const float* __restrict__ off,
                                                   unsigned short* __restrict__ Spk) {
  __shared__ __align__(16) int   pidx[80 * 4];
  __shared__ __align__(16) float pw[80 * 4];
  const int tid = threadIdx.x;
  const int j0   = blockIdx.x;         // 0..2879
  const int xcd  = j0 & 7;
  const int s    = j0 >> 3;
  const int b_hi = s / 180;
  const int t0   = s % 180;
  const int g    = t0 / 9;
  const int kk   = t0 % 9;
  const int b    = b_hi * 8 + xcd;
  const int ho0  = g * 2;

  if (tid < 80) {
    int hop = tid / 40, px = tid % 40;
    int ho = ho0 + hop;
    float dy = off[((b * 18 + 2 * kk) * HO_ + ho) * WO_ + px];
    float dx = off[((b * 18 + 2 * kk + 1) * HO_ + ho) * WO_ + px];
    float py  = (float)(2 * ho - 1 + (kk / 3)) + dy;
    float pxf = (float)(2 * px - 1 + (kk % 3)) + dx;
    float y0f = floorf(py), x0f = floorf(pxf);
    float wy1 = py - y0f, wx1 = pxf - x0f;
    float wy0 = 1.f - wy1, wx0 = 1.f - wx1;
    int y0 = (int)y0f, x0 = (int)x0f;
    int y1 = y0 + 1, x1 = x0 + 1;
    bool vy0 = (y0 >= 0) && (y0 < H_);
    bool vy1 = (y1 >= 0) && (y1 < H_);
    bool vx0 = (x0 >= 0) && (x0 < W_);
    bool vx1 = (x1 >= 0) && (x1 < W_);
    int y0c = min(max(y0, 0), H_ - 1), y1c = min(max(y1, 0), H_ - 1);
    int x0c = min(max(x0, 0), W_ - 1), x1c = min(max(x1, 0), W_ - 1);
    pidx[tid * 4 + 0] = (y0c * W_ + x0c) << 7;  pw[tid * 4 + 0] = (vy0 && vx0) ? wy0 * wx0 : 0.f;
    pidx[tid * 4 + 1] = (y0c * W_ + x1c) << 7;  pw[tid * 4 + 1] = (vy0 && vx1) ? wy0 * wx1 : 0.f;
    pidx[tid * 4 + 2] = (y1c * W_ + x0c) << 7;  pw[tid * 4 + 2] = (vy1 && vx0) ? wy1 * wx0 : 0.f;
    pidx[tid * 4 + 3] = (y1c * W_ + x1c) << 7;  pw[tid * 4 + 3] = (vy1 && vx1) ? wy1 * wx1 : 0.f;
  }
  __syncthreads();

  const unsigned short* xb = xcl + (size_t)b * (H_ * W_ * CIN_);
#pragma unroll
  for (int it = 0; it < 5; it++) {
    int i = it * 256 + tid;            // (pxh, oct), oct fastest
    int oct = i & 15;
    int pxh = i >> 4;                  // 0..79
    int4   I  = *(const int4*)&pidx[pxh * 4];
    float4 Wv = *(const float4*)&pw[pxh * 4];
    short8 c00 = *(const short8*)(xb + I.x + oct * 8);
    short8 c01 = *(const short8*)(xb + I.y + oct * 8);
    short8 c10 = *(const short8*)(xb + I.z + oct * 8);
    short8 c11 = *(const short8*)(xb + I.w + oct * 8);
    short8 r;
#pragma unroll
    for (int i2 = 0; i2 < 8; i2++) {
      float v = Wv.x * bu2f((unsigned short)c00[i2]) +
                Wv.y * bu2f((unsigned short)c01[i2]) +
                Wv.z * bu2f((unsigned short)c10[i2]) +
                Wv.w * bu2f((unsigned short)c11[i2]);
      r[i2] = (short)f2bu(v);
    }
    int p  = b * 1600 + (ho0 + (pxh / 40)) * 40 + (pxh % 40);
    int pt = p >> 4, lm = p & 15;
    int ks = kk * 4 + (oct >> 2);
    int qd = oct & 3;
    int gr = lm * 4 + ((qd + (lm >> 1)) & 3);   // bank-rotated granule
    *(short8*)&Spk[(((size_t)pt * NKS_ + ks) * 64 + gr) * 8] = r;
  }
}

// --- K2b v11 "BK=64 + counted vmcnt, asymmetric buffers": round-12's BK=64
// regressed (47.5 vs 40.5) because stage(i+1) drained at vmcnt(0) one
// compute-phase (~700cyc) after issue — HBM B-loads (~900cyc) stall every
// interval. Fix: A (L2-hot Apk, ~300cyc) double-buffered at lead-1;
// B (HBM Spk, ~900cyc) TRIPLE-buffered at lead-2. Issue order: prologue
// B0,A0,B1; body i issues A(i+1) then B(i+2); top-of-interval queue =
// [B(i),A(i),B(i+1)] -> steady vmcnt(4), vmcnt(0) only at i=17.
// Safety: A(i+1)->abuf[(i-1)&1], B(i+2)->bbuf[(i-1)%3], both issued
// post-barrier(i); all waves reached barrier(i) after lgkmcnt(0) drained
// interval i-1's reads of exactly those buffers (leads < buffer counts).
// LDS 80 KB -> 2 blocks/CU, all 400 co-resident. 18 intervals, 32 MFMA +
// 16 ds_read_b128 per wave-interval. Rotated A+B layouts (0 conflicts).
__global__ __launch_bounds__(256) void k_gemm(const unsigned short* __restrict__ Apk,
                                              const unsigned short* __restrict__ Spk,
                                              float* __restrict__ out,
                                              float* __restrict__ accum) {
  __shared__ __align__(16) unsigned short a_sh[2][8192];  // 32 KB: 128ch x 64k x2
  __shared__ __align__(16) unsigned short b_sh[3][8192];  // 48 KB: 128px x 64k x3

  const int tid = threadIdx.x;
  const int wv = tid >> 6;
  const int ln = tid & 63;
  const int lm = ln & 15;
  const int qd = ln >> 4;
  const int wch = wv & 1;              // channel wave (2)
  const int wpx = wv >> 1;             // pixel wave (2)

  const int bid = blockIdx.x;          // 0..399
  const int xcd = bid & 7;
  const int cq  = (bid >> 3) & 1;      // channel half (bid pair 8 apart -> same XCD)
  const int T   = bid >> 4;            // 0..24
  const int tile = T * 8 + xcd;        // px tile 0..199
  const int pt0 = tile * 8;            // 8 pt-groups = 128 px

  // per-k-step global slices (ks stride: A 8192 shorts, B 512 shorts)
  const unsigned short* ag = Apk + (size_t)cq * 4096 + (wv * 2) * 512 + ln * 8;
  const unsigned short* bg0 = Spk + ((size_t)(pt0 + wv * 2 + 0) * NKS_) * 512 + ln * 8;
  const unsigned short* bg1 = Spk + ((size_t)(pt0 + wv * 2 + 1) * NKS_) * 512 + ln * 8;

// A for interval i (k-steps 2i, 2i+1) into abuf[bf]: 4 loads/wave
#define STAGE_A2(i, bf) do {                                                                 \
    gl_lds16(ag + (size_t)(2 * (i)) * 8192,           &a_sh[bf][(wv * 2 + 0) * 512]);        \
    gl_lds16(ag + (size_t)(2 * (i)) * 8192 + 512,     &a_sh[bf][(wv * 2 + 1) * 512]);        \
    gl_lds16(ag + (size_t)(2 * (i) + 1) * 8192,       &a_sh[bf][4096 + (wv * 2 + 0) * 512]); \
    gl_lds16(ag + (size_t)(2 * (i) + 1) * 8192 + 512, &a_sh[bf][4096 + (wv * 2 + 1) * 512]); \
  } while (0)
// B for interval i into bbuf[bf]: 4 loads/wave
#define STAGE_B2(i, bf) do {                                                                 \
    gl_lds16(bg0 + (size_t)(2 * (i)) * 512,           &b_sh[bf][(wv * 2 + 0) * 512]);        \
    gl_lds16(bg1 + (size_t)(2 * (i)) * 512,           &b_sh[bf][(wv * 2 + 1) * 512]);        \
    gl_lds16(bg0 + (size_t)(2 * (i) + 1) * 512,       &b_sh[bf][4096 + (wv * 2 + 0) * 512]); \
    gl_lds16(bg1 + (size_t)(2 * (i) + 1) * 512,       &b_sh[bf][4096 + (wv * 2 + 1) * 512]); \
  } while (0)

  floatx4 acc[4][4];
#pragma unroll
  for (int mt = 0; mt < 4; mt++)
#pragma unroll
    for (int nt = 0; nt < 4; nt++) acc[mt][nt] = (floatx4){0.f, 0.f, 0.f, 0.f};

  const int slot = (qd + (lm >> 1)) & 3;               // bank rotation
  const int aoff0 = (wch * 64 + lm) * 32 + slot * 8;   // + mt*512 (k-step lo half)
  const int boff0 = (wpx * 4) * 512 + lm * 32 + slot * 8;  // + nt*512 (rotated)

  // prologue issue order for vmcnt accounting: B0, A0, B1
  STAGE_B2(0, 0);
  STAGE_A2(0, 0);
  STAGE_B2(1, 1);

#pragma unroll 1
  for (int i = 0; i < 18; i++) {
    // need B(i),A(i) landed; keep B(i+1) (4 loads) in flight
    if (i == 17) asm volatile("s_waitcnt vmcnt(0)" ::: "memory");
    else         asm volatile("s_waitcnt vmcnt(4)" ::: "memory");
    __builtin_amdgcn_s_barrier();
    if (i + 1 < 18) STAGE_A2(i + 1, (i + 1) & 1);   // L2-hot, lead-1 suffices
    if (i + 2 < 18) STAGE_B2(i + 2, (i + 2) % 3);   // HBM, lead-2 covers latency

    const unsigned short* al = &a_sh[i & 1][0];
    const unsigned short* bl = &b_sh[i % 3][0];
    short8 av[4], bv[4], av2[4], bv2[4];
#pragma unroll
    for (int mt = 0; mt < 4; mt++) {
      av[mt]  = *(const short8*)(al + aoff0 + mt * 512);
      av2[mt] = *(const short8*)(al + 4096 + aoff0 + mt * 512);
    }
#pragma unroll
    for (int nt = 0; nt < 4; nt++) {
      bv[nt]  = *(const short8*)(bl + boff0 + nt * 512);
      bv2[nt] = *(const short8*)(bl + 4096 + boff0 + nt * 512);
    }
#pragma unroll
    for (int mt = 0; mt < 4; mt++)
#pragma unroll
      for (int nt = 0; nt < 4; nt++)
        acc[mt][nt] = __builtin_amdgcn_mfma_f32_16x16x32_bf16(av[mt], bv[nt],
                                                              acc[mt][nt], 0, 0, 0);
#pragma unroll
    for (int mt = 0; mt < 4; mt++)
#pragma unroll
      for (int nt = 0; nt < 4; nt++)
        acc[mt][nt] = __builtin_amdgcn_mfma_f32_16x16x32_bf16(av2[mt], bv2[nt],
                                                              acc[mt][nt], 0, 0, 0);
    // drain this wave's ds_reads before it can cross the next barrier and
    // let a stage overwrite the buffers it just read
    asm volatile("s_waitcnt lgkmcnt(0)" ::: "memory");
  }
#undef STAGE_A2
#undef STAGE_B2

  // ---- C write: c = cq*128 + wch*64 + mt*16 + qd*4 + r; px = (pt0+wpx*4+nt)*16+lm
  const int cb0 = cq * 128 + wch * 64;
#pragma unroll
  for (int nt = 0; nt < 4; nt++) {
    const int p = (pt0 + wpx * 4 + nt) * 16 + lm;
    const int bb = p / 1600, rem = p - bb * 1600;
    float* ob = out + (size_t)bb * COUT_ * 1600 + rem;
#pragma unroll
    for (int mt = 0; mt < 4; mt++) {
#pragma unroll
      for (int r = 0; r < 4; r++)
        ob[(size_t)(cb0 + mt * 16 + qd * 4 + r) * 1600] = acc[mt][nt][r];
    }
  }

  // ---- fused BN stats: sum/sq-sum over this block's 128 px per channel.
  __syncthreads();                      // a_sh dead; reuse as reduction buffer
  float* red = (float*)&a_sh[0][0];     // 256 floats: s1[128], s2[128]
  red[tid & 255] = 0.f;
  __syncthreads();
#pragma unroll
  for (int mt = 0; mt < 4; mt++) {
#pragma unroll
    for (int r = 0; r < 4; r++) {
      float s = acc[mt][0][r] + acc[mt][1][r] + acc[mt][2][r] + acc[mt][3][r];
      float q = acc[mt][0][r] * acc[mt][0][r] + acc[mt][1][r] * acc[mt][1][r] +
                acc[mt][2][r] * acc[mt][2][r] + acc[mt][3][r] * acc[mt][3][r];
#pragma unroll
      for (int d = 1; d < 16; d <<= 1) {
        s += __shfl_xor(s, d, 16);
        q += __shfl_xor(q, d, 16);
      }
      if (lm == 0) {
        int lc = wch * 64 + mt * 16 + qd * 4 + r;
        atomicAdd(&red[lc], s);
        atomicAdd(&red[128 + lc], q);
      }
    }
  }
  __syncthreads();
  if (tid < 128) {
    atomicAdd(&accum[cq * 128 + tid],         red[tid]);
    atomicAdd(&accum[COUT_ + cq * 128 + tid], red[128 + tid]);
  }
}

// --------------------------- K3: BN + SiLU in place on the final out buffer
__global__ __launch_bounds__(256) void k_bn(float* __restrict__ io0,
                                            const float* __restrict__ accum,
                                            const float* __restrict__ gamma,
                                            const float* __restrict__ beta) {
  const int t = blockIdx.x * 256 + threadIdx.x;
  const int i0 = t * 4;
  const int c = (i0 / (HO_ * WO_)) % COUT_;
  const float mean = accum[c] * (1.f / NPIX_);
  const float var  = accum[COUT_ + c] * (1.f / NPIX_) - mean * mean;
  const float inv  = rsqrtf(var + 1e-5f);
  const float g  = gamma[c] * inv;
  const float be = beta[c] - mean * g;
  float4 r0 = *(const float4*)(io0 + i0);
  float v[4] = {r0.x, r0.y, r0.z, r0.w};
#pragma unroll
  for (int q = 0; q < 4; q++) {
    float u = v[q] * g + be;
    v[q] = u / (1.f + expf(-u));
  }
  *(float4*)(io0 + i0) = make_float4(v[0], v[1], v[2], v[3]);
}

// ----------------------------------------------------------------- launcher
extern "C" void kernel_launch(void* const* d_in, const int* in_sizes, int n_in,
                              void* d_out, int out_size, void* d_ws, size_t ws_size,
                              hipStream_t stream) {
  const float* x     = (const float*)d_in[0];
  const float* ow    = (const float*)d_in[1];
  const float* ob    = (const float*)d_in[2];
  const float* dw    = (const float*)d_in[3];
  const float* gamma = (const float*)d_in[5];
  const float* beta  = (const float*)d_in[6];
  float* out = (float*)d_out;

  float* off   = (float*)d_ws;                                 // 460800 f
  float* accum = off + B_ * 18 * HO_ * WO_;                    // 512 f
  unsigned short* Apk = (unsigned short*)(accum + 2 * COUT_);  // 294912 us
  unsigned short* Spk = Apk + (size_t)SK_ * COUT_;             // 29491200 us
  unsigned short* xcl = Spk + (size_t)NPIX_ * SK_;             // 13107200 us

  k_clpack<<<B_ * H_ + 36, 256, 0, stream>>>(x, ow, ob, dw, xcl, off, Apk, accum);
  k_sample_cl<<<B_ * KK_ * 20, 256, 0, stream>>>(xcl, off, Spk);
  k_gemm<<<400, 256, 0, stream>>>(Apk, Spk, out, accum);
  k_bn<<<(NPIX_ * COUT_ / 4 + 255) / 256, 256, 0, stream>>>(
      out, accum, gamma, beta);
}